// Round 7
// baseline (525.482 us; speedup 1.0000x reference)
//
#include <hip/hip_runtime.h>
#include <hip/hip_bf16.h>
#include <cstdint>

typedef __bf16 bf16;
typedef __attribute__((ext_vector_type(8))) __bf16 bf16x8;
typedef __attribute__((ext_vector_type(4))) float f32x4;

#define MFMA16(a, b, c) __builtin_amdgcn_mfma_f32_16x16x32_bf16(a, b, c, 0, 0, 0)

__device__ __forceinline__ float fast_rcp(float x) { return __builtin_amdgcn_rcpf(x); }
__device__ __forceinline__ float silu_f(float x) { return x * fast_rcp(1.f + __expf(-x)); }
__device__ __forceinline__ bf16x8 cvt8(float4 a, float4 b) {
  bf16x8 o;
  o[0]=(bf16)a.x; o[1]=(bf16)a.y; o[2]=(bf16)a.z; o[3]=(bf16)a.w;
  o[4]=(bf16)b.x; o[5]=(bf16)b.y; o[6]=(bf16)b.z; o[7]=(bf16)b.w;
  return o;
}

// ---------------- bf16 weight arena element offsets (round-2 proven) ----------------
constexpr long WB_IPW1 = 0;          // 256*192
constexpr long WB_IPW2 = 49152;      // 256*256
constexpr long WB_QKV  = 114688;     // 3*768*256
constexpr long WB_WO   = 704512;     // 3*256*256
constexpr long WB_W1   = 901120;     // 3*1024*256
constexpr long WB_W2   = 1687552;    // 3*256*1024
constexpr long WB_CPW1 = 2670592;    // 256*256
// ---------------- ws byte offsets ----------------
// WDP/W2P overlay the skipped dpw1/dpw2 arena slots (exact fit):
constexpr long O_WDP   = 4947968;    // 262144 B  (= element 2473984*2)
constexpr long O_W2P   = 5210112;    // 131072 B  (= element 2605056*2)
constexpr long O_B512  = 5472256;    // 2048 B (arena ends here)
constexpr long F_G     = 5474304;    // 1024 B
constexpr long F_AIAJ  = 5475328;    // 1048576 B
constexpr long O_KG    = 6523904;    // 2 parity bufs x 4*512*64 bf16 = 524288 B
constexpr long O_VT    = 7048192;    // 524288 B
constexpr long O_HG    = 7572480;    // 512*256 f32 = 524288 B
constexpr long O_QG    = 8096768;    // 524288 B  (end 8621056 < 8.79MB proven)

// ---------------- prep: convw (skip dpw1/dpw2) + W2P + WDP + gproj + b512 ----------------
__global__ __launch_bounds__(256) void prep_kernel(
    const float* __restrict__ s_ipw1, const float* __restrict__ s_ipw2,
    const float* __restrict__ s_qkv,  const float* __restrict__ s_wo,
    const float* __restrict__ s_w1,   const float* __restrict__ s_w2,
    const float* __restrict__ s_dpw1, const float* __restrict__ s_dpw2,
    const float* __restrict__ s_cpw1, bf16* __restrict__ dst,
    const float* __restrict__ zg, const float* __restrict__ gw1, const float* __restrict__ gb1,
    const float* __restrict__ gw2, const float* __restrict__ gb2,
    const float* __restrict__ dpb1,
    bf16* __restrict__ w2p, bf16* __restrict__ wdp,
    float* __restrict__ g, float* __restrict__ bias512)
{
  __shared__ float zs[128];
  __shared__ float ts[256];
  const int b = blockIdx.x, tid = threadIdx.x;
  if (b < 2672) {                      // weight fp32 -> bf16 arena
    long v = (long)b * 256 + tid;
    if (v >= 684032) return;
    if (v >= 618496 && v < 667648) return;   // dpw1/dpw2 slots: superseded by WDP/W2P overlay
    const float* src; long off;
    if (v < 176128) {
      if (v < 12288)      { src = s_ipw1; off = 0; }
      else if (v < 28672) { src = s_ipw2; off = 12288; }
      else                { src = s_qkv;  off = 28672; }
    } else if (v < 618496) {
      if (v < 225280)      { src = s_wo; off = 176128; }
      else if (v < 421888) { src = s_w1; off = 225280; }
      else                 { src = s_w2; off = 421888; }
    } else {
      src = s_cpw1; off = 667648;
    }
    long e = (v - off) * 4;
    float4 f = *(const float4*)&src[e];
    bf16* d = dst + off * 4 + e;
    d[0] = (bf16)f.x; d[1] = (bf16)f.y; d[2] = (bf16)f.z; d[3] = (bf16)f.w;
  } else if (b < 2704) {               // W2 -> B-frag-linear bf16 (validated)
    int f = (b - 2672) * 256 + tid;    // 8192 frags
    int l15 = f & 15, kq = (f >> 4) & 3, ks = (f >> 6) & 7, nt = f >> 9;
    int n = nt * 16 + l15, k0 = ks * 32 + kq * 8;
    float4 v0 = *(const float4*)&s_dpw2[n * 256 + k0];
    float4 v1 = *(const float4*)&s_dpw2[n * 256 + k0 + 4];
    *(bf16x8*)&w2p[(long)f * 8] = cvt8(v0, v1);
  } else if (b < 2832) {               // stacked dp_w1 (512x256) bf16 (validated)
    int v = (b - 2704) * 256 + tid;    // 32768 vec4
    int r = v >> 6, c4 = (v & 63) << 2;
    long src = (r < 256) ? ((long)r * 512 + c4) : ((long)(r - 256) * 512 + 256 + c4);
    float4 f = *(const float4*)&s_dpw1[src];
    bf16* d = &wdp[r * 256 + c4];
    d[0]=(bf16)f.x; d[1]=(bf16)f.y; d[2]=(bf16)f.z; d[3]=(bf16)f.w;
  } else if (b == 2832) {              // global MLP
    if (tid < 128) zs[tid] = zg[tid];
    __syncthreads();
    float s = gb1[tid];
    for (int k = 0; k < 128; ++k) s += zs[k] * gw1[tid * 128 + k];
    ts[tid] = silu_f(s);
    __syncthreads();
    float s2 = gb2[tid];
    for (int k = 0; k < 256; ++k) s2 += ts[k] * gw2[tid * 256 + k];
    g[tid] = s2;
  } else {                             // bias512 = [dpb1, 0]
    bias512[tid] = dpb1[tid];
    bias512[256 + tid] = 0.f;
  }
}

// ---------------- shared device helpers ----------------
// stage 16 x K fp32 LDS rows -> bf16 frag-linear af[(kk*16+m)*8+e]
__device__ __forceinline__ void stage_af(const float (*src)[264], bf16* af, int K, int tid)
{
  for (int c = tid; c < 2 * K; c += 256) {
    int m = c & 15, kk = c >> 4;
    float4 a = *(const float4*)&src[m][kk * 8];
    float4 b = *(const float4*)&src[m][kk * 8 + 4];
    *(bf16x8*)&af[(kk * 16 + m) * 8] = cvt8(a, b);
  }
}

template<int NT, int KS>
__device__ __forceinline__ void rowgemm(const bf16* __restrict__ af, const bf16* __restrict__ Wb,
                                        int ldw, int nbase, int l15, int kq, f32x4* acc)
{
#pragma unroll
  for (int ks = 0; ks < KS; ++ks) {
    bf16x8 a = *(const bf16x8*)&af[((ks * 4 + kq) * 16 + l15) * 8];
#pragma unroll
    for (int nt = 0; nt < NT; ++nt) {
      bf16x8 b = *(const bf16x8*)&Wb[(long)(nbase + nt * 16 + l15) * ldw + ks * 32 + kq * 8];
      acc[nt] = MFMA16(a, b, acc[nt]);
    }
  }
}

__device__ __forceinline__ void ln_epi(f32x4 acc[4], const float* bias,
    const float* lnsc, const float* lnbi, float (*hs)[264],
    float (*stat)[4][2], float (*mstat)[2], int l15, int kq, int w, int tid)
{
  float u[4][4];
#pragma unroll
  for (int nt = 0; nt < 4; ++nt) {
    int col = w * 64 + nt * 16 + l15;
#pragma unroll
    for (int r = 0; r < 4; ++r)
      u[nt][r] = acc[nt][r] + bias[col] + hs[kq * 4 + r][col];
  }
#pragma unroll
  for (int r = 0; r < 4; ++r) {
    float s = u[0][r] + u[1][r] + u[2][r] + u[3][r];
    float sq = u[0][r]*u[0][r] + u[1][r]*u[1][r] + u[2][r]*u[2][r] + u[3][r]*u[3][r];
    s += __shfl_xor(s, 1); sq += __shfl_xor(sq, 1);
    s += __shfl_xor(s, 2); sq += __shfl_xor(sq, 2);
    s += __shfl_xor(s, 4); sq += __shfl_xor(sq, 4);
    s += __shfl_xor(s, 8); sq += __shfl_xor(sq, 8);
    if (l15 == 0) { stat[kq * 4 + r][w][0] = s; stat[kq * 4 + r][w][1] = sq; }
  }
  __syncthreads();
  if (tid < 16) {
    float s  = stat[tid][0][0] + stat[tid][1][0] + stat[tid][2][0] + stat[tid][3][0];
    float sq = stat[tid][0][1] + stat[tid][1][1] + stat[tid][2][1] + stat[tid][3][1];
    float mean = s * (1.f / 256.f);
    float var = sq * (1.f / 256.f) - mean * mean;
    mstat[tid][0] = mean; mstat[tid][1] = rsqrtf(var + 1e-5f);
  }
  __syncthreads();
#pragma unroll
  for (int nt = 0; nt < 4; ++nt) {
    int col = w * 64 + nt * 16 + l15;
#pragma unroll
    for (int r = 0; r < 4; ++r) {
      int m = kq * 4 + r;
      hs[m][col] = (u[nt][r] - mstat[m][0]) * mstat[m][1] * lnsc[col] + lnbi[col];
    }
  }
}

// qkv for layer l from af (h frags): q -> QG, k/v -> parity buffers
__device__ __forceinline__ void qkv_emit(const bf16* af, const bf16* WB,
    int l, const float* bqkv, float* QG, bf16* kgb, bf16* vtb,
    int m0, int l15, int kq, int w)
{
  f32x4 acc[12] = {};
  rowgemm<12, 8>(af, WB + WB_QKV + (long)l * 196608, 256, w * 192, l15, kq, acc);
  bf16* kgl = kgb + (long)(l & 1) * 131072;
  bf16* vtl = vtb + (long)(l & 1) * 131072;
  const float* bq = bqkv + l * 768;
#pragma unroll
  for (int nt = 0; nt < 12; ++nt) {
    int col = w * 192 + nt * 16 + l15; float bb = bq[col];
#pragma unroll
    for (int r = 0; r < 4; ++r) {
      int m = kq * 4 + r;
      float v = acc[nt][r] + bb;
      if (col < 256) QG[(long)(m0 + m) * 256 + col] = v;
      else if (col < 512) { int c = col - 256; kgl[((c >> 6) * 512 + m0 + m) * 64 + (c & 63)] = (bf16)v; }
      else { int c = col - 512; vtl[(((c >> 6) * 64 + (c & 63)) << 9) + m0 + m] = (bf16)v; }
    }
  }
}

// ---------------- segment 1: input proj + layer-0 qkv ----------------
__global__ __launch_bounds__(256, 1) void tf_head(
    const float* __restrict__ z, const int* __restrict__ at, const float* __restrict__ emb,
    const bf16* __restrict__ WB, const float* __restrict__ g,
    const float* __restrict__ ip_b1, const float* __restrict__ ip_b2,
    const float* __restrict__ bqkv,
    float* __restrict__ HG, float* __restrict__ QG,
    bf16* __restrict__ kgb, bf16* __restrict__ vtb)
{
  __shared__ float ts[16][264];
  __shared__ float hs[16][264];
  __shared__ bf16 af[4096];
  const int tid = threadIdx.x, lane = tid & 63, w = tid >> 6;
  const int l15 = lane & 15, kq = lane >> 4;
  const int m0 = blockIdx.x * 16;

  if (tid < 192) {
    for (int m = 0; m < 16; ++m) {
      int row = m0 + m;
      ts[m][tid] = (tid < 128) ? z[row * 128 + tid] : emb[at[row] * 64 + tid - 128];
    }
  }
  __syncthreads();
  stage_af(ts, af, 192, tid);
  __syncthreads();
  {
    f32x4 acc[4] = {};
    rowgemm<4, 6>(af, WB + WB_IPW1, 192, w * 64, l15, kq, acc);
#pragma unroll
    for (int nt = 0; nt < 4; ++nt) {
      int col = w * 64 + nt * 16 + l15; float bb = ip_b1[col];
#pragma unroll
      for (int r = 0; r < 4; ++r) ts[kq * 4 + r][col] = silu_f(acc[nt][r] + bb);
    }
  }
  __syncthreads();
  stage_af(ts, af, 256, tid);
  __syncthreads();
  {
    f32x4 acc[4] = {};
    rowgemm<4, 8>(af, WB + WB_IPW2, 256, w * 64, l15, kq, acc);
#pragma unroll
    for (int nt = 0; nt < 4; ++nt) {
      int col = w * 64 + nt * 16 + l15; float bb = ip_b2[col] + g[col];
#pragma unroll
      for (int r = 0; r < 4; ++r) {
        int m = kq * 4 + r;
        float v = acc[nt][r] + bb;
        hs[m][col] = v;
        HG[(long)(m0 + m) * 256 + col] = v;
      }
    }
  }
  __syncthreads();
  stage_af(hs, af, 256, tid);
  __syncthreads();
  qkv_emit(af, WB, 0, bqkv, QG, kgb, vtb, m0, l15, kq, w);
}

// ---------------- segment 2..4: attn + proj/LN1 + FFN/LN2 (+next qkv | +heads) ----------------
template<int LAST>
__global__ __launch_bounds__(256, 1) void tf_layer(
    int l, const bf16* __restrict__ WB,
    const float* __restrict__ bqkv, const float* __restrict__ bo,
    const float* __restrict__ ln1s, const float* __restrict__ ln1b,
    const float* __restrict__ b1, const float* __restrict__ b2,
    const float* __restrict__ ln2s, const float* __restrict__ ln2b,
    float* __restrict__ HG, float* __restrict__ QG,
    bf16* __restrict__ kgb, bf16* __restrict__ vtb,
    const bf16* __restrict__ WDP, const float* __restrict__ b512, float* __restrict__ aiaj,
    const float* __restrict__ cpb1, const float* __restrict__ cpw2,
    const float* __restrict__ cpb2, float* __restrict__ xout)
{
  __shared__ float ts[16][264];
  __shared__ float hs[16][264];
  __shared__ bf16 af[4096];
  __shared__ bf16 af2[4096];
  __shared__ bf16 plds[4][1024];
  __shared__ float stat[16][4][2];
  __shared__ float mstat[16][2];
  const int tid = threadIdx.x, lane = tid & 63, w = tid >> 6;
  const int l15 = lane & 15, kq = lane >> 4, ehi = l15 >> 3, elo = l15 & 7;
  const int m0 = blockIdx.x * 16;

  for (int m = 0; m < 16; ++m) {
    hs[m][tid] = HG[(long)(m0 + m) * 256 + tid];
    ts[m][tid] = QG[(long)(m0 + m) * 256 + tid];
  }
  __syncthreads();

  // ---- attention: wave w = head w, rows m0..m0+15, 512 keys, exact softmax ----
  {
    bf16x8 qa[2];
#pragma unroll
    for (int ksq = 0; ksq < 2; ++ksq) {
      float4 f0 = *(const float4*)&ts[l15][w * 64 + ksq * 32 + kq * 8];
      float4 f1 = *(const float4*)&ts[l15][w * 64 + ksq * 32 + kq * 8 + 4];
      qa[ksq] = cvt8(f0, f1);
    }
    f32x4 accS[32];
#pragma unroll
    for (int nt = 0; nt < 32; ++nt) accS[nt] = (f32x4){0.f, 0.f, 0.f, 0.f};
    const bf16* kgl = kgb + (long)(l & 1) * 131072 + w * 32768;
#pragma unroll 4
    for (int nt = 0; nt < 32; ++nt) {
      const bf16* kr = &kgl[(nt * 16 + l15) * 64 + kq * 8];
      bf16x8 kb0 = *(const bf16x8*)kr;
      bf16x8 kb1 = *(const bf16x8*)(kr + 32);
      accS[nt] = MFMA16(qa[0], kb0, accS[nt]);
      accS[nt] = MFMA16(qa[1], kb1, accS[nt]);
    }
#pragma unroll
    for (int r = 0; r < 4; ++r) {
      float mx = accS[0][r];
#pragma unroll
      for (int nt = 1; nt < 32; ++nt) mx = fmaxf(mx, accS[nt][r]);
      mx = fmaxf(mx, __shfl_xor(mx, 1)); mx = fmaxf(mx, __shfl_xor(mx, 2));
      mx = fmaxf(mx, __shfl_xor(mx, 4)); mx = fmaxf(mx, __shfl_xor(mx, 8));
      float s = 0.f;
#pragma unroll
      for (int nt = 0; nt < 32; ++nt) { float pe = __expf((accS[nt][r] - mx) * 0.125f); accS[nt][r] = pe; s += pe; }
      s += __shfl_xor(s, 1); s += __shfl_xor(s, 2); s += __shfl_xor(s, 4); s += __shfl_xor(s, 8);
      float iv = fast_rcp(s);
#pragma unroll
      for (int nt = 0; nt < 32; ++nt) accS[nt][r] *= iv;
    }
    const bf16* vtl = vtb + (long)(l & 1) * 131072 + w * 32768;
    bf16* pw = &plds[w][0];
    f32x4 accO[4] = {};
    for (int kc = 0; kc < 8; ++kc) {          // 64-key chunks
#pragma unroll
      for (int ntl = 0; ntl < 4; ++ntl) {
        int nt = kc * 4 + ntl;
#pragma unroll
        for (int r = 0; r < 4; ++r)
          pw[((ntl * 2 + ehi) * 16 + kq * 4 + r) * 8 + elo] = (bf16)accS[nt][r];
      }
#pragma unroll
      for (int ksl = 0; ksl < 2; ++ksl) {
        bf16x8 pa = *(const bf16x8*)&pw[((ksl * 4 + kq) * 16 + l15) * 8];
#pragma unroll
        for (int ntd = 0; ntd < 4; ++ntd) {
          bf16x8 vb = *(const bf16x8*)&vtl[(ntd * 16 + l15) * 512 + kc * 64 + ksl * 32 + kq * 8];
          accO[ntd] = MFMA16(pa, vb, accO[ntd]);
        }
      }
    }
#pragma unroll
    for (int ntd = 0; ntd < 4; ++ntd)
#pragma unroll
      for (int r = 0; r < 4; ++r)
        ts[kq * 4 + r][w * 64 + ntd * 16 + l15] = accO[ntd][r];
  }
  __syncthreads();
  // ---- proj + bias + residual + LN1 -> hs ----
  stage_af(ts, af, 256, tid);
  __syncthreads();
  {
    f32x4 acc[4] = {};
    rowgemm<4, 8>(af, WB + WB_WO + (long)l * 65536, 256, w * 64, l15, kq, acc);
    ln_epi(acc, bo + l * 256, ln1s + l * 256, ln1b + l * 256, hs, stat, mstat, l15, kq, w, tid);
  }
  __syncthreads();
  // ---- FFN + residual + LN2 -> hs ----
  stage_af(hs, af, 256, tid);
  __syncthreads();
  {
    f32x4 f2[4] = {};
    for (int kc = 0; kc < 4; ++kc) {
      f32x4 a1[4] = {};
      rowgemm<4, 8>(af, WB + WB_W1 + (long)l * 262144, 256, kc * 256 + w * 64, l15, kq, a1);
      const float* b1l = b1 + l * 1024 + kc * 256;
#pragma unroll
      for (int nt = 0; nt < 4; ++nt) {
        int ck = w * 64 + nt * 16 + l15; float bb = b1l[ck];
#pragma unroll
        for (int r = 0; r < 4; ++r) {
          float v = fmaxf(a1[nt][r] + bb, 0.f);
          af2[((w * 8 + nt * 2 + ehi) * 16 + kq * 4 + r) * 8 + elo] = (bf16)v;
        }
      }
      __syncthreads();
      rowgemm<4, 8>(af2, WB + WB_W2 + (long)l * 262144 + kc * 256, 1024, w * 64, l15, kq, f2);
      __syncthreads();
    }
    ln_epi(f2, b2 + l * 256, ln2s + l * 256, ln2b + l * 256, hs, stat, mstat, l15, kq, w, tid);
  }
  __syncthreads();

  if constexpr (!LAST) {
    for (int m = 0; m < 16; ++m)
      HG[(long)(m0 + m) * 256 + tid] = hs[m][tid];
    stage_af(hs, af, 256, tid);
    __syncthreads();
    qkv_emit(af, WB, l + 1, bqkv, QG, kgb, vtb, m0, l15, kq, w);
  } else {
    stage_af(hs, af, 256, tid);
    __syncthreads();
    {   // aiaj = h @ WDP^T + b512
      f32x4 acc[8] = {};
      rowgemm<8, 8>(af, WDP, 256, w * 128, l15, kq, acc);
#pragma unroll
      for (int nt = 0; nt < 8; ++nt) {
        int col = w * 128 + nt * 16 + l15; float bb = b512[col];
#pragma unroll
        for (int r = 0; r < 4; ++r)
          aiaj[(long)(m0 + kq * 4 + r) * 512 + col] = acc[nt][r] + bb;
      }
    }
    {   // coord head
      f32x4 acc[4] = {};
      rowgemm<4, 8>(af, WB + WB_CPW1, 256, w * 64, l15, kq, acc);
#pragma unroll
      for (int nt = 0; nt < 4; ++nt) {
        int col = w * 64 + nt * 16 + l15; float bb = cpb1[col];
#pragma unroll
        for (int r = 0; r < 4; ++r) ts[kq * 4 + r][col] = silu_f(acc[nt][r] + bb);
      }
    }
    __syncthreads();
    if (tid < 48) {
      int row = tid / 3, c = tid - row * 3;
      float s = cpb2[c];
      const float* wp = &cpw2[c * 256];
      for (int k = 0; k < 256; ++k) s += ts[row][k] * wp[k];
      xout[(long)(m0 + row) * 3 + c] = s;
    }
  }
}

// ---------------- fused pair/dist kernel — validated (99 µs) ----------------
__global__ __launch_bounds__(256, 2) void pair2_kernel(
    const float* __restrict__ ai, const float* __restrict__ aj,
    const bf16* __restrict__ W2P, const float* __restrict__ b2g,
    const float* __restrict__ w3g, const float* __restrict__ b3p,
    float* __restrict__ dout)
{
  __shared__ float ai_s[256];
  __shared__ bf16  t_s[64 * 256];
  __shared__ float part[64][4];
  const int tid = threadIdx.x, lane = tid & 63, w = tid >> 6;
  const int l15 = lane & 15, kq = lane >> 4;
  const int i = blockIdx.x >> 1, half = blockIdx.x & 1;
  const float b3v = b3p[0];

  ai_s[tid] = ai[(long)i * 512 + tid];

  bf16x8 w2r[4][8];
  float b2v[4], w3v[4];
#pragma unroll
  for (int nt = 0; nt < 4; ++nt) {
    int ntg = w * 4 + nt;
#pragma unroll
    for (int ks = 0; ks < 8; ++ks)
      w2r[nt][ks] = *(const bf16x8*)&W2P[(long)((((ntg * 8 + ks) * 4 + kq) * 16) + l15) * 8];
    b2v[nt] = b2g[ntg * 16 + l15];
    w3v[nt] = w3g[ntg * 16 + l15];
  }
  __syncthreads();

  for (int jc = half * 4; jc < half * 4 + 4; ++jc) {
    const int j0 = jc * 64;
    const float* ajp = aj + (long)(j0 + lane) * 512;
#pragma unroll
    for (int r = 0; r < 8; ++r) {
      int kk = w + 4 * r;
      float4 a0 = *(const float4*)(ajp + kk * 8);
      float4 a1 = *(const float4*)(ajp + kk * 8 + 4);
      const float* aip = ai_s + kk * 8;
      bf16x8 tv;
      tv[0] = (bf16)silu_f(a0.x + aip[0]); tv[1] = (bf16)silu_f(a0.y + aip[1]);
      tv[2] = (bf16)silu_f(a0.z + aip[2]); tv[3] = (bf16)silu_f(a0.w + aip[3]);
      tv[4] = (bf16)silu_f(a1.x + aip[4]); tv[5] = (bf16)silu_f(a1.y + aip[5]);
      tv[6] = (bf16)silu_f(a1.z + aip[6]); tv[7] = (bf16)silu_f(a1.w + aip[7]);
      *(bf16x8*)&t_s[(kk * 64 + lane) * 8] = tv;
    }
    __syncthreads();

    f32x4 acc[4][4] = {};
#pragma unroll
    for (int ks = 0; ks < 8; ++ks) {
      bf16x8 af[4];
#pragma unroll
      for (int Mt = 0; Mt < 4; ++Mt)
        af[Mt] = *(const bf16x8*)&t_s[((ks * 4 + kq) * 64 + Mt * 16 + l15) * 8];
#pragma unroll
      for (int nt = 0; nt < 4; ++nt)
#pragma unroll
        for (int Mt = 0; Mt < 4; ++Mt)
          acc[Mt][nt] = MFMA16(af[Mt], w2r[nt][ks], acc[Mt][nt]);
    }

#pragma unroll
    for (int Mt = 0; Mt < 4; ++Mt)
#pragma unroll
      for (int r = 0; r < 4; ++r) {
        float s = silu_f(acc[Mt][0][r] + b2v[0]) * w3v[0]
                + silu_f(acc[Mt][1][r] + b2v[1]) * w3v[1]
                + silu_f(acc[Mt][2][r] + b2v[2]) * w3v[2]
                + silu_f(acc[Mt][3][r] + b2v[3]) * w3v[3];
        s += __shfl_xor(s, 1); s += __shfl_xor(s, 2);
        s += __shfl_xor(s, 4); s += __shfl_xor(s, 8);
        if (l15 == 0) part[Mt * 16 + kq * 4 + r][w] = s;
      }
    __syncthreads();
    if (tid < 64) {
      float s = part[tid][0] + part[tid][1] + part[tid][2] + part[tid][3] + b3v;
      float dd = fmaxf(s, 0.f) + log1pf(__expf(-fabsf(s)));
      dout[(long)i * 512 + j0 + tid] = dd;
    }
    __syncthreads();
  }
}

// ---------------- symmetrize dist in place ----------------
__global__ __launch_bounds__(256) void sym_kernel(float* __restrict__ dist)
{
  int idx = blockIdx.x * 256 + threadIdx.x;
  int i = idx >> 9, j = idx & 511;
  if (i < j) {
    float a = dist[idx];
    float b = dist[(long)j * 512 + i];
    float m = 0.5f * (a + b);
    dist[idx] = m;
    dist[(long)j * 512 + i] = m;
  }
}

extern "C" void kernel_launch(void* const* d_in, const int* in_sizes, int n_in,
                              void* d_out, int out_size, void* d_ws, size_t ws_size,
                              hipStream_t stream) {
  const float* z        = (const float*)d_in[0];
  const float* z_global = (const float*)d_in[1];
  const int*   atom_t   = (const int*)d_in[2];
  const float* emb      = (const float*)d_in[3];
  const float* ip_w1 = (const float*)d_in[4];  const float* ip_b1 = (const float*)d_in[5];
  const float* ip_w2 = (const float*)d_in[6];  const float* ip_b2 = (const float*)d_in[7];
  const float* gp_w1 = (const float*)d_in[8];  const float* gp_b1 = (const float*)d_in[9];
  const float* gp_w2 = (const float*)d_in[10]; const float* gp_b2 = (const float*)d_in[11];
  const float* wqkv  = (const float*)d_in[12]; const float* bqkv  = (const float*)d_in[13];
  const float* wo    = (const float*)d_in[14]; const float* bo    = (const float*)d_in[15];
  const float* ln1s  = (const float*)d_in[16]; const float* ln1b  = (const float*)d_in[17];
  const float* w1    = (const float*)d_in[18]; const float* b1    = (const float*)d_in[19];
  const float* w2    = (const float*)d_in[20]; const float* b2    = (const float*)d_in[21];
  const float* ln2s  = (const float*)d_in[22]; const float* ln2b  = (const float*)d_in[23];
  const float* dpw1  = (const float*)d_in[24]; const float* dpb1  = (const float*)d_in[25];
  const float* dpw2  = (const float*)d_in[26]; const float* dpb2  = (const float*)d_in[27];
  const float* dpw3  = (const float*)d_in[28]; const float* dpb3  = (const float*)d_in[29];
  const float* cpw1  = (const float*)d_in[30]; const float* cpb1  = (const float*)d_in[31];
  const float* cpw2  = (const float*)d_in[32]; const float* cpb2  = (const float*)d_in[33];

  char* ws = (char*)d_ws;
  bf16*  WB   = (bf16*)ws;
  bf16*  WDP  = (bf16*)(ws + O_WDP);
  bf16*  W2P  = (bf16*)(ws + O_W2P);
  float* b512 = (float*)(ws + O_B512);
  float* g    = (float*)(ws + F_G);
  float* aiaj = (float*)(ws + F_AIAJ);
  bf16*  KG   = (bf16*)(ws + O_KG);
  bf16*  VT   = (bf16*)(ws + O_VT);
  float* HG   = (float*)(ws + O_HG);
  float* QG   = (float*)(ws + O_QG);
  float* out  = (float*)d_out;
  float* xout = out;
  float* dist = out + 1536;

  prep_kernel<<<2834, 256, 0, stream>>>(ip_w1, ip_w2, wqkv, wo, w1, w2, dpw1, dpw2, cpw1, WB,
      z_global, gp_w1, gp_b1, gp_w2, gp_b2, dpb1, W2P, WDP, g, b512);

  tf_head<<<32, 256, 0, stream>>>(z, atom_t, emb, WB, g, ip_b1, ip_b2, bqkv, HG, QG, KG, VT);
  tf_layer<0><<<32, 256, 0, stream>>>(0, WB, bqkv, bo, ln1s, ln1b, b1, b2, ln2s, ln2b,
      HG, QG, KG, VT, nullptr, nullptr, nullptr, nullptr, nullptr, nullptr, nullptr);
  tf_layer<0><<<32, 256, 0, stream>>>(1, WB, bqkv, bo, ln1s, ln1b, b1, b2, ln2s, ln2b,
      HG, QG, KG, VT, nullptr, nullptr, nullptr, nullptr, nullptr, nullptr, nullptr);
  tf_layer<1><<<32, 256, 0, stream>>>(2, WB, bqkv, bo, ln1s, ln1b, b1, b2, ln2s, ln2b,
      HG, QG, KG, VT, WDP, b512, aiaj, cpb1, cpw2, cpb2, xout);

  pair2_kernel<<<1024, 256, 0, stream>>>(aiaj, aiaj + 256, W2P, dpb2, dpw3, dpb3, dist);
  sym_kernel<<<1024, 256, 0, stream>>>(dist);
}

// Round 8
// 393.341 us; speedup vs baseline: 1.3359x; 1.3359x over previous
//
#include <hip/hip_runtime.h>
#include <hip/hip_bf16.h>
#include <cstdint>

typedef __bf16 bf16;
typedef __attribute__((ext_vector_type(8))) __bf16 bf16x8;
typedef __attribute__((ext_vector_type(4))) float f32x4;

#define MFMA16(a, b, c) __builtin_amdgcn_mfma_f32_16x16x32_bf16(a, b, c, 0, 0, 0)

__device__ __forceinline__ float fast_rcp(float x) { return __builtin_amdgcn_rcpf(x); }
__device__ __forceinline__ float silu_f(float x) { return x * fast_rcp(1.f + __expf(-x)); }
__device__ __forceinline__ bf16x8 cvt8(float4 a, float4 b) {
  bf16x8 o;
  o[0]=(bf16)a.x; o[1]=(bf16)a.y; o[2]=(bf16)a.z; o[3]=(bf16)a.w;
  o[4]=(bf16)b.x; o[5]=(bf16)b.y; o[6]=(bf16)b.z; o[7]=(bf16)b.w;
  return o;
}

// ---------------- ws layout ----------------
// bf16 weight arena (element offsets into (bf16*)ws) — round-2 proven
constexpr long WB_IPW1 = 0;          // 256*192
constexpr long WB_IPW2 = 49152;      // 256*256
constexpr long WB_QKV  = 114688;     // 3*768*256
constexpr long WB_WO   = 704512;     // 3*256*256
constexpr long WB_W1   = 901120;     // 3*1024*256
constexpr long WB_W2   = 1687552;    // 3*256*1024
constexpr long WB_CPW1 = 2670592;    // 256*256
// float buffers (byte offsets) — round-5 proven region map
constexpr long F_ZIN = 5472256;                 // 512*192 f32
constexpr long F_G   = F_ZIN + 512L*192*4;      // 256 f32
constexpr long F_H   = F_G + 1024;              // 512*256 f32
constexpr long F_QKV = F_H + 512L*256*4;        // qk 512*512 f32 (1MB of 1.5MB region)
constexpr long F_S   = F_QKV + 512L*768*4;      // 4*512*512 f32 (S / ff1 / later aiaj)
constexpr long F_VT  = F_S + 4L*512*512*4;      // 4*64*512 bf16
constexpr long F_O   = F_VT + 4L*64*512*2;      // 512*256 f32
constexpr long F_T1  = F_O + 512L*256*4;        // 512*256 f32
constexpr long O_W2P  = F_T1 + 512L*256*4;      // 8192*8 bf16 = 131072 B
constexpr long O_WDP  = O_W2P + 131072;         // 512*256 bf16 = 262144 B
constexpr long O_B512 = O_WDP + 262144;         // 512 f32

// ---------------- prep: convw + zin + W2P perm + WDP pack + gproj + bias512 (round-5 verbatim) ----------------
__global__ __launch_bounds__(256) void prep_kernel(
    const float* __restrict__ s_ipw1, const float* __restrict__ s_ipw2,
    const float* __restrict__ s_qkv,  const float* __restrict__ s_wo,
    const float* __restrict__ s_w1,   const float* __restrict__ s_w2,
    const float* __restrict__ s_dpw1, const float* __restrict__ s_dpw2,
    const float* __restrict__ s_cpw1, bf16* __restrict__ dst,
    const float* __restrict__ z, const int* __restrict__ at, const float* __restrict__ emb,
    const float* __restrict__ zg, const float* __restrict__ gw1, const float* __restrict__ gb1,
    const float* __restrict__ gw2, const float* __restrict__ gb2,
    const float* __restrict__ dpb1,
    float* __restrict__ zi, bf16* __restrict__ w2p, bf16* __restrict__ wdp,
    float* __restrict__ g, float* __restrict__ bias512)
{
  __shared__ float zs[128];
  __shared__ float ts[256];
  const int b = blockIdx.x, tid = threadIdx.x;
  if (b < 2672) {
    long v = (long)b * 256 + tid;
    if (v >= 684032) return;
    const float* src; long off;
    if (v < 176128) {
      if (v < 12288)      { src = s_ipw1; off = 0; }
      else if (v < 28672) { src = s_ipw2; off = 12288; }
      else                { src = s_qkv;  off = 28672; }
    } else if (v < 618496) {
      if (v < 225280)      { src = s_wo; off = 176128; }
      else if (v < 421888) { src = s_w1; off = 225280; }
      else                 { src = s_w2; off = 421888; }
    } else {
      if (v < 651264)      { src = s_dpw1; off = 618496; }
      else if (v < 667648) { src = s_dpw2; off = 651264; }
      else                 { src = s_cpw1; off = 667648; }
    }
    long e = (v - off) * 4;
    float4 f = *(const float4*)&src[e];
    bf16* d = dst + off * 4 + e;
    d[0] = (bf16)f.x; d[1] = (bf16)f.y; d[2] = (bf16)f.z; d[3] = (bf16)f.w;
  } else if (b < 3056) {
    int idx = (b - 2672) * 256 + tid;
    int n = idx / 192, c = idx - n * 192;
    zi[idx] = (c < 128) ? z[n * 128 + c] : emb[at[n] * 64 + (c - 128)];
  } else if (b < 3088) {
    int f = (b - 3056) * 256 + tid;
    int l15 = f & 15, kq = (f >> 4) & 3, ks = (f >> 6) & 7, nt = f >> 9;
    int n = nt * 16 + l15, k0 = ks * 32 + kq * 8;
    float4 v0 = *(const float4*)&s_dpw2[n * 256 + k0];
    float4 v1 = *(const float4*)&s_dpw2[n * 256 + k0 + 4];
    *(bf16x8*)&w2p[(long)f * 8] = cvt8(v0, v1);
  } else if (b < 3216) {
    int v = (b - 3088) * 256 + tid;
    int r = v >> 6, c4 = (v & 63) << 2;
    long src = (r < 256) ? ((long)r * 512 + c4) : ((long)(r - 256) * 512 + 256 + c4);
    float4 f = *(const float4*)&s_dpw1[src];
    bf16* d = &wdp[r * 256 + c4];
    d[0]=(bf16)f.x; d[1]=(bf16)f.y; d[2]=(bf16)f.z; d[3]=(bf16)f.w;
  } else if (b == 3216) {
    if (tid < 128) zs[tid] = zg[tid];
    __syncthreads();
    float s = gb1[tid];
    for (int k = 0; k < 128; ++k) s += zs[k] * gw1[tid * 128 + k];
    ts[tid] = silu_f(s);
    __syncthreads();
    float s2 = gb2[tid];
    for (int k = 0; k < 256; ++k) s2 += ts[k] * gw2[tid * 256 + k];
    g[tid] = s2;
  } else {
    bias512[tid] = dpb1[tid];
    bias512[256 + tid] = 0.f;
  }
}

// ---------------- generic MFMA GEMM — round-2/5 verbatim ----------------
template<int ACT, typename WT>
__global__ __launch_bounds__(256) void gemm_kernel(
    const float* __restrict__ A, int lda, long sA,
    const WT* __restrict__ W, int ldw, long sW,
    const float* __restrict__ bias,
    const float* __restrict__ R, int ldr, long sR,
    float* __restrict__ C, int ldc, long sC, int K)
{
  const int bz = blockIdx.z;
  A += (long)bz * sA;  W += (long)bz * sW;  C += (long)bz * sC;
  if (R) R += (long)bz * sR;
  const int m0 = blockIdx.x * 64, n0 = blockIdx.y * 64;
  __shared__ bf16 As[64][72];
  __shared__ bf16 Ws[64][72];
  const int tid = threadIdx.x;
  const int lane = tid & 63, wid = tid >> 6;
  const int wm = (wid & 1) * 32, wn = (wid >> 1) * 32;
  const int rr = lane & 15, kg = (lane >> 4) << 3;
  f32x4 acc[2][2] = {};
  for (int k0 = 0; k0 < K; k0 += 64) {
#pragma unroll
    for (int r = 0; r < 4; ++r) {
      int lin = tid + r * 256;
      int row = lin >> 4, kc = (lin & 15) << 2;
      {
        const float* p = &A[(long)(m0 + row) * lda + k0 + kc];
        float4 v = *(const float4*)p;
        As[row][kc] = (bf16)v.x; As[row][kc + 1] = (bf16)v.y;
        As[row][kc + 2] = (bf16)v.z; As[row][kc + 3] = (bf16)v.w;
      }
      {
        const WT* p = &W[(long)(n0 + row) * ldw + k0 + kc];
        if constexpr (sizeof(WT) == 4) {
          float4 v = *(const float4*)p;
          Ws[row][kc] = (bf16)v.x; Ws[row][kc + 1] = (bf16)v.y;
          Ws[row][kc + 2] = (bf16)v.z; Ws[row][kc + 3] = (bf16)v.w;
        } else {
          *(uint2*)&Ws[row][kc] = *(const uint2*)p;
        }
      }
    }
    __syncthreads();
#pragma unroll
    for (int ks = 0; ks < 2; ++ks) {
      const int kk = ks * 32 + kg;
      bf16x8 a0 = *(const bf16x8*)&As[wm + rr][kk];
      bf16x8 a1 = *(const bf16x8*)&As[wm + 16 + rr][kk];
      bf16x8 b0 = *(const bf16x8*)&Ws[wn + rr][kk];
      bf16x8 b1 = *(const bf16x8*)&Ws[wn + 16 + rr][kk];
      acc[0][0] = MFMA16(a0, b0, acc[0][0]);
      acc[0][1] = MFMA16(a0, b1, acc[0][1]);
      acc[1][0] = MFMA16(a1, b0, acc[1][0]);
      acc[1][1] = MFMA16(a1, b1, acc[1][1]);
    }
    __syncthreads();
  }
  const int rg = lane >> 4;
#pragma unroll
  for (int mi = 0; mi < 2; ++mi)
#pragma unroll
    for (int ni = 0; ni < 2; ++ni)
#pragma unroll
      for (int r = 0; r < 4; ++r) {
        int gm = m0 + wm + mi * 16 + rg * 4 + r;
        int gn = n0 + wn + ni * 16 + rr;
        float v = acc[mi][ni][r];
        if (bias) v += bias[gn];
        if (R) v += R[(long)gm * ldr + gn];
        if (ACT == 1) v = silu_f(v);
        else if (ACT == 2) v = fmaxf(v, 0.f);
        C[(long)gm * ldc + gn] = v;
      }
}

// ---------------- qkv GEMM: q/k -> qk f32 [512][512]; v -> Vt bf16 [h][d][n] ----------------
__global__ __launch_bounds__(256) void gemm_qkv_kernel(
    const float* __restrict__ A,
    const bf16* __restrict__ W,
    const float* __restrict__ bias,
    float* __restrict__ qk, bf16* __restrict__ vt)
{
  const int m0 = blockIdx.x * 64, n0 = blockIdx.y * 64;
  __shared__ bf16 As[64][72];
  __shared__ bf16 Ws[64][72];
  const int tid = threadIdx.x;
  const int lane = tid & 63, wid = tid >> 6;
  const int wm = (wid & 1) * 32, wn = (wid >> 1) * 32;
  const int rr = lane & 15, kg = (lane >> 4) << 3;
  f32x4 acc[2][2] = {};
  for (int k0 = 0; k0 < 256; k0 += 64) {
#pragma unroll
    for (int r = 0; r < 4; ++r) {
      int lin = tid + r * 256;
      int row = lin >> 4, kc = (lin & 15) << 2;
      {
        const float* p = &A[(long)(m0 + row) * 256 + k0 + kc];
        float4 v = *(const float4*)p;
        As[row][kc] = (bf16)v.x; As[row][kc + 1] = (bf16)v.y;
        As[row][kc + 2] = (bf16)v.z; As[row][kc + 3] = (bf16)v.w;
      }
      *(uint2*)&Ws[row][kc] = *(const uint2*)&W[(long)(n0 + row) * 256 + k0 + kc];
    }
    __syncthreads();
#pragma unroll
    for (int ks = 0; ks < 2; ++ks) {
      const int kk = ks * 32 + kg;
      bf16x8 a0 = *(const bf16x8*)&As[wm + rr][kk];
      bf16x8 a1 = *(const bf16x8*)&As[wm + 16 + rr][kk];
      bf16x8 b0 = *(const bf16x8*)&Ws[wn + rr][kk];
      bf16x8 b1 = *(const bf16x8*)&Ws[wn + 16 + rr][kk];
      acc[0][0] = MFMA16(a0, b0, acc[0][0]);
      acc[0][1] = MFMA16(a0, b1, acc[0][1]);
      acc[1][0] = MFMA16(a1, b0, acc[1][0]);
      acc[1][1] = MFMA16(a1, b1, acc[1][1]);
    }
    __syncthreads();
  }
  const int rg = lane >> 4;
#pragma unroll
  for (int mi = 0; mi < 2; ++mi)
#pragma unroll
    for (int ni = 0; ni < 2; ++ni)
#pragma unroll
      for (int r = 0; r < 4; ++r) {
        int gm = m0 + wm + mi * 16 + rg * 4 + r;
        int gn = n0 + wn + ni * 16 + rr;
        float v = acc[mi][ni][r] + bias[gn];
        if (gn < 512) {
          qk[(long)gm * 512 + gn] = v;
        } else {
          int c = gn - 512;   // head = c>>6, d = c&63
          vt[(long)(c >> 6) * 32768 + (long)(c & 63) * 512 + gm] = (bf16)v;
        }
      }
}

// ---------------- fused softmax + PV: grid (512 rows, 4 heads) ----------------
__global__ __launch_bounds__(256) void softmax_pv_kernel(
    const float* __restrict__ S, const bf16* __restrict__ Vt, float* __restrict__ o)
{
  const int row = blockIdx.x, h = blockIdx.y;
  const float* srow = S + ((long)h * 512 + row) * 512;
  __shared__ float p_s[512];
  __shared__ float red[4];
  __shared__ float red2[4];
  __shared__ float part[64][4];
  const int tid = threadIdx.x;
  float a = srow[tid] * 0.125f, b = srow[tid + 256] * 0.125f;
  float m = fmaxf(a, b);
#pragma unroll
  for (int t = 1; t < 64; t <<= 1) m = fmaxf(m, __shfl_xor(m, t));
  int wid = tid >> 6;
  if ((tid & 63) == 0) red[wid] = m;
  __syncthreads();
  m = fmaxf(fmaxf(red[0], red[1]), fmaxf(red[2], red[3]));
  float e0 = __expf(a - m), e1 = __expf(b - m);
  float s = e0 + e1;
#pragma unroll
  for (int t = 1; t < 64; t <<= 1) s += __shfl_xor(s, t);
  if ((tid & 63) == 0) red2[wid] = s;
  __syncthreads();
  s = red2[0] + red2[1] + red2[2] + red2[3];
  float inv = fast_rcp(s);
  p_s[tid] = e0 * inv; p_s[tid + 256] = e1 * inv;
  __syncthreads();
  // PV: thread (d = tid&63, kc = tid>>6) sums 128 keys
  const int d = tid & 63, kc = tid >> 6;
  const bf16* vp = Vt + (long)h * 32768 + (long)d * 512 + kc * 128;
  const float* pp = &p_s[kc * 128];
  float acc = 0.f;
#pragma unroll
  for (int k = 0; k < 128; k += 8) {
    bf16x8 vv = *(const bf16x8*)&vp[k];
    acc += pp[k]     * (float)vv[0] + pp[k + 1] * (float)vv[1]
         + pp[k + 2] * (float)vv[2] + pp[k + 3] * (float)vv[3]
         + pp[k + 4] * (float)vv[4] + pp[k + 5] * (float)vv[5]
         + pp[k + 6] * (float)vv[6] + pp[k + 7] * (float)vv[7];
  }
  part[d][kc] = acc;
  __syncthreads();
  if (tid < 64)
    o[(long)row * 256 + h * 64 + tid] = part[tid][0] + part[tid][1] + part[tid][2] + part[tid][3];
}

// ---------------- LayerNorm rows of 256 — validated ----------------
__global__ __launch_bounds__(256) void ln_kernel(
    const float* __restrict__ X, const float* __restrict__ sc,
    const float* __restrict__ bi, float* __restrict__ Y)
{
  int row = blockIdx.x, tid = threadIdx.x;
  float v = X[(long)row * 256 + tid];
  float s = v;
#pragma unroll
  for (int o = 1; o < 64; o <<= 1) s += __shfl_xor(s, o);
  __shared__ float r1[4];
  __shared__ float r2[4];
  if ((tid & 63) == 0) r1[tid >> 6] = s;
  __syncthreads();
  float mean = (r1[0] + r1[1] + r1[2] + r1[3]) * (1.f / 256.f);
  float d = v - mean;
  float t = d * d;
#pragma unroll
  for (int o = 1; o < 64; o <<= 1) t += __shfl_xor(t, o);
  if ((tid & 63) == 0) r2[tid >> 6] = t;
  __syncthreads();
  float var = (r2[0] + r2[1] + r2[2] + r2[3]) * (1.f / 256.f);
  Y[(long)row * 256 + tid] = d * rsqrtf(var + 1e-5f) * sc[tid] + bi[tid];
}

// ---------------- fused pair/dist kernel — validated math, grid 2048 ----------------
__global__ __launch_bounds__(256, 2) void pair2_kernel(
    const float* __restrict__ ai, const float* __restrict__ aj,
    const bf16* __restrict__ W2P, const float* __restrict__ b2g,
    const float* __restrict__ w3g, const float* __restrict__ b3p,
    float* __restrict__ dout)
{
  __shared__ float ai_s[256];
  __shared__ bf16  t_s[64 * 256];
  __shared__ float part[64][4];
  const int tid = threadIdx.x, lane = tid & 63, w = tid >> 6;
  const int l15 = lane & 15, kq = lane >> 4;
  const int i = blockIdx.x >> 2, q = blockIdx.x & 3;
  const float b3v = b3p[0];

  ai_s[tid] = ai[(long)i * 512 + tid];

  bf16x8 w2r[4][8];
  float b2v[4], w3v[4];
#pragma unroll
  for (int nt = 0; nt < 4; ++nt) {
    int ntg = w * 4 + nt;
#pragma unroll
    for (int ks = 0; ks < 8; ++ks)
      w2r[nt][ks] = *(const bf16x8*)&W2P[(long)((((ntg * 8 + ks) * 4 + kq) * 16) + l15) * 8];
    b2v[nt] = b2g[ntg * 16 + l15];
    w3v[nt] = w3g[ntg * 16 + l15];
  }
  __syncthreads();

  for (int jc = q * 2; jc < q * 2 + 2; ++jc) {
    const int j0 = jc * 64;
    const float* ajp = aj + (long)(j0 + lane) * 512;
#pragma unroll
    for (int r = 0; r < 8; ++r) {
      int kk = w + 4 * r;
      float4 a0 = *(const float4*)(ajp + kk * 8);
      float4 a1 = *(const float4*)(ajp + kk * 8 + 4);
      const float* aip = ai_s + kk * 8;
      bf16x8 tv;
      tv[0] = (bf16)silu_f(a0.x + aip[0]); tv[1] = (bf16)silu_f(a0.y + aip[1]);
      tv[2] = (bf16)silu_f(a0.z + aip[2]); tv[3] = (bf16)silu_f(a0.w + aip[3]);
      tv[4] = (bf16)silu_f(a1.x + aip[4]); tv[5] = (bf16)silu_f(a1.y + aip[5]);
      tv[6] = (bf16)silu_f(a1.z + aip[6]); tv[7] = (bf16)silu_f(a1.w + aip[7]);
      *(bf16x8*)&t_s[(kk * 64 + lane) * 8] = tv;
    }
    __syncthreads();

    f32x4 acc[4][4] = {};
#pragma unroll
    for (int ks = 0; ks < 8; ++ks) {
      bf16x8 af[4];
#pragma unroll
      for (int Mt = 0; Mt < 4; ++Mt)
        af[Mt] = *(const bf16x8*)&t_s[((ks * 4 + kq) * 64 + Mt * 16 + l15) * 8];
#pragma unroll
      for (int nt = 0; nt < 4; ++nt)
#pragma unroll
        for (int Mt = 0; Mt < 4; ++Mt)
          acc[Mt][nt] = MFMA16(af[Mt], w2r[nt][ks], acc[Mt][nt]);
    }

#pragma unroll
    for (int Mt = 0; Mt < 4; ++Mt)
#pragma unroll
      for (int r = 0; r < 4; ++r) {
        float s = silu_f(acc[Mt][0][r] + b2v[0]) * w3v[0]
                + silu_f(acc[Mt][1][r] + b2v[1]) * w3v[1]
                + silu_f(acc[Mt][2][r] + b2v[2]) * w3v[2]
                + silu_f(acc[Mt][3][r] + b2v[3]) * w3v[3];
        s += __shfl_xor(s, 1); s += __shfl_xor(s, 2);
        s += __shfl_xor(s, 4); s += __shfl_xor(s, 8);
        if (l15 == 0) part[Mt * 16 + kq * 4 + r][w] = s;
      }
    __syncthreads();
    if (tid < 64) {
      float s = part[tid][0] + part[tid][1] + part[tid][2] + part[tid][3] + b3v;
      float dd = fmaxf(s, 0.f) + log1pf(__expf(-fabsf(s)));
      dout[(long)i * 512 + j0 + tid] = dd;
    }
    __syncthreads();
  }
}

// ---------------- symmetrize dist in place ----------------
__global__ __launch_bounds__(256) void sym_kernel(float* __restrict__ dist)
{
  int idx = blockIdx.x * 256 + threadIdx.x;
  int i = idx >> 9, j = idx & 511;
  if (i < j) {
    float a = dist[idx];
    float b = dist[(long)j * 512 + i];
    float m = 0.5f * (a + b);
    dist[idx] = m;
    dist[(long)j * 512 + i] = m;
  }
}

// ---------------- coordinate head final 256->3 ----------------
__global__ __launch_bounds__(256) void coord_kernel(
    const float* __restrict__ ct, const float* __restrict__ w2,
    const float* __restrict__ b2, float* __restrict__ out)
{
  int t = blockIdx.x * 256 + threadIdx.x;
  if (t >= 1536) return;
  int row = t / 3, c = t - row * 3;
  float s = b2[c];
  const float* a = &ct[(long)row * 256];
  const float* wp = &w2[c * 256];
  for (int k = 0; k < 256; ++k) s += a[k] * wp[k];
  out[t] = s;
}

extern "C" void kernel_launch(void* const* d_in, const int* in_sizes, int n_in,
                              void* d_out, int out_size, void* d_ws, size_t ws_size,
                              hipStream_t stream) {
  const float* z        = (const float*)d_in[0];
  const float* z_global = (const float*)d_in[1];
  const int*   atom_t   = (const int*)d_in[2];
  const float* emb      = (const float*)d_in[3];
  const float* ip_w1 = (const float*)d_in[4];  const float* ip_b1 = (const float*)d_in[5];
  const float* ip_w2 = (const float*)d_in[6];  const float* ip_b2 = (const float*)d_in[7];
  const float* gp_w1 = (const float*)d_in[8];  const float* gp_b1 = (const float*)d_in[9];
  const float* gp_w2 = (const float*)d_in[10]; const float* gp_b2 = (const float*)d_in[11];
  const float* wqkv  = (const float*)d_in[12]; const float* bqkv  = (const float*)d_in[13];
  const float* wo    = (const float*)d_in[14]; const float* bo    = (const float*)d_in[15];
  const float* ln1s  = (const float*)d_in[16]; const float* ln1b  = (const float*)d_in[17];
  const float* w1    = (const float*)d_in[18]; const float* b1    = (const float*)d_in[19];
  const float* w2    = (const float*)d_in[20]; const float* b2    = (const float*)d_in[21];
  const float* ln2s  = (const float*)d_in[22]; const float* ln2b  = (const float*)d_in[23];
  const float* dpw1  = (const float*)d_in[24]; const float* dpb1  = (const float*)d_in[25];
  const float* dpw2  = (const float*)d_in[26]; const float* dpb2  = (const float*)d_in[27];
  const float* dpw3  = (const float*)d_in[28]; const float* dpb3  = (const float*)d_in[29];
  const float* cpw1  = (const float*)d_in[30]; const float* cpb1  = (const float*)d_in[31];
  const float* cpw2  = (const float*)d_in[32]; const float* cpb2  = (const float*)d_in[33];

  char* ws = (char*)d_ws;
  bf16*  WB   = (bf16*)ws;
  float* zin  = (float*)(ws + F_ZIN);
  float* g    = (float*)(ws + F_G);
  float* h    = (float*)(ws + F_H);
  float* qk   = (float*)(ws + F_QKV);
  float* S    = (float*)(ws + F_S);
  bf16*  Vt   = (bf16*)(ws + F_VT);
  float* o    = (float*)(ws + F_O);
  float* t1   = (float*)(ws + F_T1);
  bf16*  W2P  = (bf16*)(ws + O_W2P);
  bf16*  WDP  = (bf16*)(ws + O_WDP);
  float* b512 = (float*)(ws + O_B512);
  float* ff1  = S;                   // reuse during transformer
  float* aiaj = S;                   // reuse after transformer
  float* out  = (float*)d_out;
  float* xout = out;
  float* dist = out + 1536;

  prep_kernel<<<3218, 256, 0, stream>>>(ip_w1, ip_w2, wqkv, wo, w1, w2, dpw1, dpw2, cpw1, WB,
      z, atom_t, emb, z_global, gp_w1, gp_b1, gp_w2, gp_b2, dpb1,
      zin, W2P, WDP, g, b512);

  gemm_kernel<1, bf16><<<dim3(8, 4, 1), 256, 0, stream>>>(zin, 192, 0, WB + WB_IPW1, 192, 0,
      ip_b1, nullptr, 0, 0, t1, 256, 0, 192);
  gemm_kernel<0, bf16><<<dim3(8, 4, 1), 256, 0, stream>>>(t1, 256, 0, WB + WB_IPW2, 256, 0,
      ip_b2, g, 0, 0, h, 256, 0, 256);

  for (int l = 0; l < 3; ++l) {
    gemm_qkv_kernel<<<dim3(8, 12), 256, 0, stream>>>(h,
        WB + WB_QKV + (long)l * 196608, bqkv + l * 768, qk, Vt);
    gemm_kernel<0, float><<<dim3(8, 8, 4), 256, 0, stream>>>(qk, 512, 64, qk + 256, 512, 64,
        nullptr, nullptr, 0, 0, S, 512, 262144, 64);
    softmax_pv_kernel<<<dim3(512, 4), 256, 0, stream>>>(S, Vt, o);
    gemm_kernel<0, bf16><<<dim3(8, 4, 1), 256, 0, stream>>>(o, 256, 0,
        WB + WB_WO + (long)l * 65536, 256, 0, bo + l * 256, h, 256, 0, t1, 256, 0, 256);
    ln_kernel<<<512, 256, 0, stream>>>(t1, ln1s + l * 256, ln1b + l * 256, h);
    gemm_kernel<2, bf16><<<dim3(8, 16, 1), 256, 0, stream>>>(h, 256, 0,
        WB + WB_W1 + (long)l * 262144, 256, 0, b1 + l * 1024, nullptr, 0, 0, ff1, 1024, 0, 256);
    gemm_kernel<0, bf16><<<dim3(8, 4, 1), 256, 0, stream>>>(ff1, 1024, 0,
        WB + WB_W2 + (long)l * 262144, 1024, 0, b2 + l * 256, h, 256, 0, t1, 256, 0, 1024);
    ln_kernel<<<512, 256, 0, stream>>>(t1, ln2s + l * 256, ln2b + l * 256, h);
  }

  // [ai | aj] = h @ [dpw1_lo ; dpw1_hi]^T + [b1 | 0]
  gemm_kernel<0, bf16><<<dim3(8, 8, 1), 256, 0, stream>>>(h, 256, 0, WDP, 256, 0,
      b512, nullptr, 0, 0, aiaj, 512, 0, 256);
  pair2_kernel<<<2048, 256, 0, stream>>>(aiaj, aiaj + 256, W2P, dpb2, dpw3, dpb3, dist);
  sym_kernel<<<1024, 256, 0, stream>>>(dist);
  gemm_kernel<1, bf16><<<dim3(8, 4, 1), 256, 0, stream>>>(h, 256, 0, WB + WB_CPW1, 256, 0,
      cpb1, nullptr, 0, 0, t1, 256, 0, 256);
  coord_kernel<<<6, 256, 0, stream>>>(t1, cpw2, cpb2, xout);
}

// Round 9
// 375.799 us; speedup vs baseline: 1.3983x; 1.0467x over previous
//
#include <hip/hip_runtime.h>
#include <hip/hip_bf16.h>
#include <cstdint>

typedef __bf16 bf16;
typedef __attribute__((ext_vector_type(8))) __bf16 bf16x8;
typedef __attribute__((ext_vector_type(4))) float f32x4;

#define MFMA16(a, b, c) __builtin_amdgcn_mfma_f32_16x16x32_bf16(a, b, c, 0, 0, 0)

__device__ __forceinline__ float fast_rcp(float x) { return __builtin_amdgcn_rcpf(x); }
__device__ __forceinline__ float silu_f(float x) { return x * fast_rcp(1.f + __expf(-x)); }
__device__ __forceinline__ bf16x8 cvt8(float4 a, float4 b) {
  bf16x8 o;
  o[0]=(bf16)a.x; o[1]=(bf16)a.y; o[2]=(bf16)a.z; o[3]=(bf16)a.w;
  o[4]=(bf16)b.x; o[5]=(bf16)b.y; o[6]=(bf16)b.z; o[7]=(bf16)b.w;
  return o;
}

// ---------------- ws layout ----------------
// bf16 weight arena (element offsets into (bf16*)ws) — round-2 proven
constexpr long WB_IPW1 = 0;          // 256*192
constexpr long WB_IPW2 = 49152;      // 256*256
constexpr long WB_QKV  = 114688;     // 3*768*256
constexpr long WB_WO   = 704512;     // 3*256*256
constexpr long WB_W1   = 901120;     // 3*1024*256
constexpr long WB_W2   = 1687552;    // 3*256*1024
constexpr long WB_CPW1 = 2670592;    // 256*256
// float buffers (byte offsets) — round-5 proven
constexpr long F_ZIN = 5472256;                 // 512*192 f32
constexpr long F_G   = F_ZIN + 512L*192*4;      // 256 f32
constexpr long F_H   = F_G + 1024;              // 512*256 f32
constexpr long F_QKV = F_H + 512L*256*4;        // 512*768 f32
constexpr long F_S   = F_QKV + 512L*768*4;      // 4*512*512 f32 (S / ff1 / later aiaj)
constexpr long F_VT  = F_S + 4L*512*512*4;      // 4*64*512 bf16
constexpr long F_O   = F_VT + 4L*64*512*2;      // 512*256 f32
constexpr long F_T1  = F_O + 512L*256*4;        // 512*256 f32
constexpr long O_W2P  = F_T1 + 512L*256*4;      // 8192*8 bf16 = 131072 B
constexpr long O_WDP  = O_W2P + 131072;         // 512*256 bf16 = 262144 B
constexpr long O_B512 = O_WDP + 262144;         // 512 f32

// ---------------- prep — round-5 verbatim ----------------
__global__ __launch_bounds__(256) void prep_kernel(
    const float* __restrict__ s_ipw1, const float* __restrict__ s_ipw2,
    const float* __restrict__ s_qkv,  const float* __restrict__ s_wo,
    const float* __restrict__ s_w1,   const float* __restrict__ s_w2,
    const float* __restrict__ s_dpw1, const float* __restrict__ s_dpw2,
    const float* __restrict__ s_cpw1, bf16* __restrict__ dst,
    const float* __restrict__ z, const int* __restrict__ at, const float* __restrict__ emb,
    const float* __restrict__ zg, const float* __restrict__ gw1, const float* __restrict__ gb1,
    const float* __restrict__ gw2, const float* __restrict__ gb2,
    const float* __restrict__ dpb1,
    float* __restrict__ zi, bf16* __restrict__ w2p, bf16* __restrict__ wdp,
    float* __restrict__ g, float* __restrict__ bias512)
{
  __shared__ float zs[128];
  __shared__ float ts[256];
  const int b = blockIdx.x, tid = threadIdx.x;
  if (b < 2672) {
    long v = (long)b * 256 + tid;
    if (v >= 684032) return;
    const float* src; long off;
    if (v < 176128) {
      if (v < 12288)      { src = s_ipw1; off = 0; }
      else if (v < 28672) { src = s_ipw2; off = 12288; }
      else                { src = s_qkv;  off = 28672; }
    } else if (v < 618496) {
      if (v < 225280)      { src = s_wo; off = 176128; }
      else if (v < 421888) { src = s_w1; off = 225280; }
      else                 { src = s_w2; off = 421888; }
    } else {
      if (v < 651264)      { src = s_dpw1; off = 618496; }
      else if (v < 667648) { src = s_dpw2; off = 651264; }
      else                 { src = s_cpw1; off = 667648; }
    }
    long e = (v - off) * 4;
    float4 f = *(const float4*)&src[e];
    bf16* d = dst + off * 4 + e;
    d[0] = (bf16)f.x; d[1] = (bf16)f.y; d[2] = (bf16)f.z; d[3] = (bf16)f.w;
  } else if (b < 3056) {
    int idx = (b - 2672) * 256 + tid;
    int n = idx / 192, c = idx - n * 192;
    zi[idx] = (c < 128) ? z[n * 128 + c] : emb[at[n] * 64 + (c - 128)];
  } else if (b < 3088) {
    int f = (b - 3056) * 256 + tid;
    int l15 = f & 15, kq = (f >> 4) & 3, ks = (f >> 6) & 7, nt = f >> 9;
    int n = nt * 16 + l15, k0 = ks * 32 + kq * 8;
    float4 v0 = *(const float4*)&s_dpw2[n * 256 + k0];
    float4 v1 = *(const float4*)&s_dpw2[n * 256 + k0 + 4];
    *(bf16x8*)&w2p[(long)f * 8] = cvt8(v0, v1);
  } else if (b < 3216) {
    int v = (b - 3088) * 256 + tid;
    int r = v >> 6, c4 = (v & 63) << 2;
    long src = (r < 256) ? ((long)r * 512 + c4) : ((long)(r - 256) * 512 + 256 + c4);
    float4 f = *(const float4*)&s_dpw1[src];
    bf16* d = &wdp[r * 256 + c4];
    d[0]=(bf16)f.x; d[1]=(bf16)f.y; d[2]=(bf16)f.z; d[3]=(bf16)f.w;
  } else if (b == 3216) {
    if (tid < 128) zs[tid] = zg[tid];
    __syncthreads();
    float s = gb1[tid];
    for (int k = 0; k < 128; ++k) s += zs[k] * gw1[tid * 128 + k];
    ts[tid] = silu_f(s);
    __syncthreads();
    float s2 = gb2[tid];
    for (int k = 0; k < 256; ++k) s2 += ts[k] * gw2[tid * 256 + k];
    g[tid] = s2;
  } else {
    bias512[tid] = dpb1[tid];
    bias512[256 + tid] = 0.f;
  }
}

// ---------------- generic MFMA GEMM — round-2/5 verbatim ----------------
template<int ACT, typename WT>
__global__ __launch_bounds__(256) void gemm_kernel(
    const float* __restrict__ A, int lda, long sA,
    const WT* __restrict__ W, int ldw, long sW,
    const float* __restrict__ bias,
    const float* __restrict__ R, int ldr, long sR,
    float* __restrict__ C, int ldc, long sC, int K)
{
  const int bz = blockIdx.z;
  A += (long)bz * sA;  W += (long)bz * sW;  C += (long)bz * sC;
  if (R) R += (long)bz * sR;
  const int m0 = blockIdx.x * 64, n0 = blockIdx.y * 64;
  __shared__ bf16 As[64][72];
  __shared__ bf16 Ws[64][72];
  const int tid = threadIdx.x;
  const int lane = tid & 63, wid = tid >> 6;
  const int wm = (wid & 1) * 32, wn = (wid >> 1) * 32;
  const int rr = lane & 15, kg = (lane >> 4) << 3;
  f32x4 acc[2][2] = {};
  for (int k0 = 0; k0 < K; k0 += 64) {
#pragma unroll
    for (int r = 0; r < 4; ++r) {
      int lin = tid + r * 256;
      int row = lin >> 4, kc = (lin & 15) << 2;
      {
        const float* p = &A[(long)(m0 + row) * lda + k0 + kc];
        float4 v = *(const float4*)p;
        As[row][kc] = (bf16)v.x; As[row][kc + 1] = (bf16)v.y;
        As[row][kc + 2] = (bf16)v.z; As[row][kc + 3] = (bf16)v.w;
      }
      {
        const WT* p = &W[(long)(n0 + row) * ldw + k0 + kc];
        if constexpr (sizeof(WT) == 4) {
          float4 v = *(const float4*)p;
          Ws[row][kc] = (bf16)v.x; Ws[row][kc + 1] = (bf16)v.y;
          Ws[row][kc + 2] = (bf16)v.z; Ws[row][kc + 3] = (bf16)v.w;
        } else {
          *(uint2*)&Ws[row][kc] = *(const uint2*)p;
        }
      }
    }
    __syncthreads();
#pragma unroll
    for (int ks = 0; ks < 2; ++ks) {
      const int kk = ks * 32 + kg;
      bf16x8 a0 = *(const bf16x8*)&As[wm + rr][kk];
      bf16x8 a1 = *(const bf16x8*)&As[wm + 16 + rr][kk];
      bf16x8 b0 = *(const bf16x8*)&Ws[wn + rr][kk];
      bf16x8 b1 = *(const bf16x8*)&Ws[wn + 16 + rr][kk];
      acc[0][0] = MFMA16(a0, b0, acc[0][0]);
      acc[0][1] = MFMA16(a0, b1, acc[0][1]);
      acc[1][0] = MFMA16(a1, b0, acc[1][0]);
      acc[1][1] = MFMA16(a1, b1, acc[1][1]);
    }
    __syncthreads();
  }
  const int rg = lane >> 4;
#pragma unroll
  for (int mi = 0; mi < 2; ++mi)
#pragma unroll
    for (int ni = 0; ni < 2; ++ni)
#pragma unroll
      for (int r = 0; r < 4; ++r) {
        int gm = m0 + wm + mi * 16 + rg * 4 + r;
        int gn = n0 + wn + ni * 16 + rr;
        float v = acc[mi][ni][r];
        if (bias) v += bias[gn];
        if (R) v += R[(long)gm * ldr + gn];
        if (ACT == 1) v = silu_f(v);
        else if (ACT == 2) v = fmaxf(v, 0.f);
        C[(long)gm * ldc + gn] = v;
      }
}

// ---------------- row softmax — round-5 verbatim ----------------
__global__ __launch_bounds__(256) void softmax_kernel(float* __restrict__ S)
{
  long base = ((long)blockIdx.y * 512 + blockIdx.x) * 512;
  float* row = S + base;
  int tid = threadIdx.x;
  float a = row[tid] * 0.125f, b = row[tid + 256] * 0.125f;
  float m = fmaxf(a, b);
#pragma unroll
  for (int o = 1; o < 64; o <<= 1) m = fmaxf(m, __shfl_xor(m, o));
  __shared__ float red[4];
  __shared__ float red2[4];
  int wid = tid >> 6;
  if ((tid & 63) == 0) red[wid] = m;
  __syncthreads();
  m = fmaxf(fmaxf(red[0], red[1]), fmaxf(red[2], red[3]));
  float e0 = __expf(a - m), e1 = __expf(b - m);
  float s = e0 + e1;
#pragma unroll
  for (int o = 1; o < 64; o <<= 1) s += __shfl_xor(s, o);
  if ((tid & 63) == 0) red2[wid] = s;
  __syncthreads();
  s = red2[0] + red2[1] + red2[2] + red2[3];
  float inv = fast_rcp(s);
  row[tid] = e0 * inv; row[tid + 256] = e1 * inv;
}

// ---------------- V transpose — round-5 verbatim ----------------
__global__ __launch_bounds__(256) void vt_kernel(const float* __restrict__ qkv, bf16* __restrict__ vt)
{
  int idx = blockIdx.x * 256 + threadIdx.x;
  int hh = idx >> 15;
  int r = idx & 32767;
  int d = r >> 9, n = r & 511;
  vt[idx] = (bf16)qkv[(long)n * 768 + 512 + hh * 64 + d];
}

// ---------------- LayerNorm — round-5 verbatim ----------------
__global__ __launch_bounds__(256) void ln_kernel(
    const float* __restrict__ X, const float* __restrict__ sc,
    const float* __restrict__ bi, float* __restrict__ Y)
{
  int row = blockIdx.x, tid = threadIdx.x;
  float v = X[(long)row * 256 + tid];
  float s = v;
#pragma unroll
  for (int o = 1; o < 64; o <<= 1) s += __shfl_xor(s, o);
  __shared__ float r1[4];
  __shared__ float r2[4];
  if ((tid & 63) == 0) r1[tid >> 6] = s;
  __syncthreads();
  float mean = (r1[0] + r1[1] + r1[2] + r1[3]) * (1.f / 256.f);
  float d = v - mean;
  float t = d * d;
#pragma unroll
  for (int o = 1; o < 64; o <<= 1) t += __shfl_xor(t, o);
  if ((tid & 63) == 0) r2[tid >> 6] = t;
  __syncthreads();
  float var = (r2[0] + r2[1] + r2[2] + r2[3]) * (1.f / 256.f);
  Y[(long)row * 256 + tid] = d * rsqrtf(var + 1e-5f) * sc[tid] + bi[tid];
}

// ---------------- fused pair/dist kernel v3: stream W2 frags from L2 (no reg cache) ----------------
// Hypothesis test: VGPR 128 (w2r cache) sits on the occupancy bin edge (waves/SIMD
// halve at 64/128/256). Streaming B-frags drops VGPR to ~80-100 -> 4 waves/SIMD,
// 4 blocks/CU. W2P (128KB) is L2-resident; extra L2 reads hidden by occupancy.
__global__ __launch_bounds__(256, 2) void pair2_kernel(
    const float* __restrict__ ai, const float* __restrict__ aj,
    const bf16* __restrict__ W2P, const float* __restrict__ b2g,
    const float* __restrict__ w3g, const float* __restrict__ b3p,
    float* __restrict__ dout)
{
  __shared__ float ai_s[256];
  __shared__ bf16  t_s[64 * 256];
  __shared__ float part[64][4];
  const int tid = threadIdx.x, lane = tid & 63, w = tid >> 6;
  const int l15 = lane & 15, kq = lane >> 4;
  const int i = blockIdx.x >> 1, half = blockIdx.x & 1;
  const float b3v = b3p[0];

  ai_s[tid] = ai[(long)i * 512 + tid];

  float b2v[4], w3v[4];
#pragma unroll
  for (int nt = 0; nt < 4; ++nt) {
    int ntg = w * 4 + nt;
    b2v[nt] = b2g[ntg * 16 + l15];
    w3v[nt] = w3g[ntg * 16 + l15];
  }
  // per-lane base into frag-linear W2P for this wave's n-range:
  // frag(ntg, ks) at ((((ntg*8 + ks)*4 + kq)*16) + l15)*8
  const bf16* w2base = W2P + ((long)(((w * 4) * 8 * 4 + kq) * 16 + l15)) * 8;
  __syncthreads();

  for (int jc = half * 4; jc < half * 4 + 4; ++jc) {
    const int j0 = jc * 64;
    const float* ajp = aj + (long)(j0 + lane) * 512;
#pragma unroll
    for (int r = 0; r < 8; ++r) {
      int kk = w + 4 * r;
      float4 a0 = *(const float4*)(ajp + kk * 8);
      float4 a1 = *(const float4*)(ajp + kk * 8 + 4);
      const float* aip = ai_s + kk * 8;
      bf16x8 tv;
      tv[0] = (bf16)silu_f(a0.x + aip[0]); tv[1] = (bf16)silu_f(a0.y + aip[1]);
      tv[2] = (bf16)silu_f(a0.z + aip[2]); tv[3] = (bf16)silu_f(a0.w + aip[3]);
      tv[4] = (bf16)silu_f(a1.x + aip[4]); tv[5] = (bf16)silu_f(a1.y + aip[5]);
      tv[6] = (bf16)silu_f(a1.z + aip[6]); tv[7] = (bf16)silu_f(a1.w + aip[7]);
      *(bf16x8*)&t_s[(kk * 64 + lane) * 8] = tv;
    }
    __syncthreads();

    f32x4 acc[4][4] = {};
#pragma unroll
    for (int ks = 0; ks < 8; ++ks) {
      bf16x8 af[4];
#pragma unroll
      for (int Mt = 0; Mt < 4; ++Mt)
        af[Mt] = *(const bf16x8*)&t_s[((ks * 4 + kq) * 64 + Mt * 16 + l15) * 8];
#pragma unroll
      for (int nt = 0; nt < 4; ++nt) {
        // frag offset for (ntg = w*4+nt, ks): (nt*8 + ks) * 4*16*8 elements from w2base
        bf16x8 bfv = *(const bf16x8*)(w2base + (long)(nt * 8 + ks) * 512);
#pragma unroll
        for (int Mt = 0; Mt < 4; ++Mt)
          acc[Mt][nt] = MFMA16(af[Mt], bfv, acc[Mt][nt]);
      }
    }

#pragma unroll
    for (int Mt = 0; Mt < 4; ++Mt)
#pragma unroll
      for (int r = 0; r < 4; ++r) {
        float s = silu_f(acc[Mt][0][r] + b2v[0]) * w3v[0]
                + silu_f(acc[Mt][1][r] + b2v[1]) * w3v[1]
                + silu_f(acc[Mt][2][r] + b2v[2]) * w3v[2]
                + silu_f(acc[Mt][3][r] + b2v[3]) * w3v[3];
        s += __shfl_xor(s, 1); s += __shfl_xor(s, 2);
        s += __shfl_xor(s, 4); s += __shfl_xor(s, 8);
        if (l15 == 0) part[Mt * 16 + kq * 4 + r][w] = s;
      }
    __syncthreads();
    if (tid < 64) {
      float s = part[tid][0] + part[tid][1] + part[tid][2] + part[tid][3] + b3v;
      float dd = fmaxf(s, 0.f) + log1pf(__expf(-fabsf(s)));
      dout[(long)i * 512 + j0 + tid] = dd;
    }
    __syncthreads();
  }
}

// ---------------- symmetrize ----------------
__global__ __launch_bounds__(256) void sym_kernel(float* __restrict__ dist)
{
  int idx = blockIdx.x * 256 + threadIdx.x;
  int i = idx >> 9, j = idx & 511;
  if (i < j) {
    float a = dist[idx];
    float b = dist[(long)j * 512 + i];
    float m = 0.5f * (a + b);
    dist[idx] = m;
    dist[(long)j * 512 + i] = m;
  }
}

// ---------------- coordinate head ----------------
__global__ __launch_bounds__(256) void coord_kernel(
    const float* __restrict__ ct, const float* __restrict__ w2,
    const float* __restrict__ b2, float* __restrict__ out)
{
  int t = blockIdx.x * 256 + threadIdx.x;
  if (t >= 1536) return;
  int row = t / 3, c = t - row * 3;
  float s = b2[c];
  const float* a = &ct[(long)row * 256];
  const float* wp = &w2[c * 256];
  for (int k = 0; k < 256; ++k) s += a[k] * wp[k];
  out[t] = s;
}

extern "C" void kernel_launch(void* const* d_in, const int* in_sizes, int n_in,
                              void* d_out, int out_size, void* d_ws, size_t ws_size,
                              hipStream_t stream) {
  const float* z        = (const float*)d_in[0];
  const float* z_global = (const float*)d_in[1];
  const int*   atom_t   = (const int*)d_in[2];
  const float* emb      = (const float*)d_in[3];
  const float* ip_w1 = (const float*)d_in[4];  const float* ip_b1 = (const float*)d_in[5];
  const float* ip_w2 = (const float*)d_in[6];  const float* ip_b2 = (const float*)d_in[7];
  const float* gp_w1 = (const float*)d_in[8];  const float* gp_b1 = (const float*)d_in[9];
  const float* gp_w2 = (const float*)d_in[10]; const float* gp_b2 = (const float*)d_in[11];
  const float* wqkv  = (const float*)d_in[12]; const float* bqkv  = (const float*)d_in[13];
  const float* wo    = (const float*)d_in[14]; const float* bo    = (const float*)d_in[15];
  const float* ln1s  = (const float*)d_in[16]; const float* ln1b  = (const float*)d_in[17];
  const float* w1    = (const float*)d_in[18]; const float* b1    = (const float*)d_in[19];
  const float* w2    = (const float*)d_in[20]; const float* b2    = (const float*)d_in[21];
  const float* ln2s  = (const float*)d_in[22]; const float* ln2b  = (const float*)d_in[23];
  const float* dpw1  = (const float*)d_in[24]; const float* dpb1  = (const float*)d_in[25];
  const float* dpw2  = (const float*)d_in[26]; const float* dpb2  = (const float*)d_in[27];
  const float* dpw3  = (const float*)d_in[28]; const float* dpb3  = (const float*)d_in[29];
  const float* cpw1  = (const float*)d_in[30]; const float* cpb1  = (const float*)d_in[31];
  const float* cpw2  = (const float*)d_in[32]; const float* cpb2  = (const float*)d_in[33];

  char* ws = (char*)d_ws;
  bf16*  WB   = (bf16*)ws;
  float* zin  = (float*)(ws + F_ZIN);
  float* g    = (float*)(ws + F_G);
  float* h    = (float*)(ws + F_H);
  float* qkv  = (float*)(ws + F_QKV);
  float* S    = (float*)(ws + F_S);
  bf16*  Vt   = (bf16*)(ws + F_VT);
  float* o    = (float*)(ws + F_O);
  float* t1   = (float*)(ws + F_T1);
  bf16*  W2P  = (bf16*)(ws + O_W2P);
  bf16*  WDP  = (bf16*)(ws + O_WDP);
  float* b512 = (float*)(ws + O_B512);
  float* ff1  = S;                   // reuse during transformer
  float* aiaj = S;                   // reuse after transformer
  float* out  = (float*)d_out;
  float* xout = out;
  float* dist = out + 1536;

  prep_kernel<<<3218, 256, 0, stream>>>(ip_w1, ip_w2, wqkv, wo, w1, w2, dpw1, dpw2, cpw1, WB,
      z, atom_t, emb, z_global, gp_w1, gp_b1, gp_w2, gp_b2, dpb1,
      zin, W2P, WDP, g, b512);

  gemm_kernel<1, bf16><<<dim3(8, 4, 1), 256, 0, stream>>>(zin, 192, 0, WB + WB_IPW1, 192, 0,
      ip_b1, nullptr, 0, 0, t1, 256, 0, 192);
  gemm_kernel<0, bf16><<<dim3(8, 4, 1), 256, 0, stream>>>(t1, 256, 0, WB + WB_IPW2, 256, 0,
      ip_b2, g, 0, 0, h, 256, 0, 256);

  for (int l = 0; l < 3; ++l) {
    const bf16* wq = WB + WB_QKV + (long)l * 768 * 256;
    gemm_kernel<0, bf16><<<dim3(8, 12, 1), 256, 0, stream>>>(h, 256, 0, wq, 256, 0,
        bqkv + l * 768, nullptr, 0, 0, qkv, 768, 0, 256);
    gemm_kernel<0, float><<<dim3(8, 8, 4), 256, 0, stream>>>(qkv, 768, 64, qkv + 256, 768, 64,
        nullptr, nullptr, 0, 0, S, 512, 262144, 64);
    softmax_kernel<<<dim3(512, 4), 256, 0, stream>>>(S);
    vt_kernel<<<512, 256, 0, stream>>>(qkv, Vt);
    gemm_kernel<0, bf16><<<dim3(8, 1, 4), 256, 0, stream>>>(S, 512, 262144, Vt, 512, 32768,
        nullptr, nullptr, 0, 0, o, 256, 64, 512);
    gemm_kernel<0, bf16><<<dim3(8, 4, 1), 256, 0, stream>>>(o, 256, 0,
        WB + WB_WO + (long)l * 65536, 256, 0, bo + l * 256, h, 256, 0, t1, 256, 0, 256);
    ln_kernel<<<512, 256, 0, stream>>>(t1, ln1s + l * 256, ln1b + l * 256, h);
    gemm_kernel<2, bf16><<<dim3(8, 16, 1), 256, 0, stream>>>(h, 256, 0,
        WB + WB_W1 + (long)l * 262144, 256, 0, b1 + l * 1024, nullptr, 0, 0, ff1, 1024, 0, 256);
    gemm_kernel<0, bf16><<<dim3(8, 4, 1), 256, 0, stream>>>(ff1, 1024, 0,
        WB + WB_W2 + (long)l * 262144, 1024, 0, b2 + l * 256, h, 256, 0, t1, 256, 0, 1024);
    ln_kernel<<<512, 256, 0, stream>>>(t1, ln2s + l * 256, ln2b + l * 256, h);
  }

  // [ai | aj] = h @ [dpw1_lo ; dpw1_hi]^T + [b1 | 0]
  gemm_kernel<0, bf16><<<dim3(8, 8, 1), 256, 0, stream>>>(h, 256, 0, WDP, 256, 0,
      b512, nullptr, 0, 0, aiaj, 512, 0, 256);
  pair2_kernel<<<1024, 256, 0, stream>>>(aiaj, aiaj + 256, W2P, dpb2, dpw3, dpb3, dist);
  sym_kernel<<<1024, 256, 0, stream>>>(dist);
  gemm_kernel<1, bf16><<<dim3(8, 4, 1), 256, 0, stream>>>(h, 256, 0, WB + WB_CPW1, 256, 0,
      cpb1, nullptr, 0, 0, t1, 256, 0, 256);
  coord_kernel<<<6, 256, 0, stream>>>(t1, cpw2, cpb2, xout);
}

// Round 10
// 355.645 us; speedup vs baseline: 1.4775x; 1.0567x over previous
//
#include <hip/hip_runtime.h>
#include <hip/hip_bf16.h>
#include <cstdint>

typedef __bf16 bf16;
typedef __attribute__((ext_vector_type(8))) __bf16 bf16x8;
typedef __attribute__((ext_vector_type(4))) float f32x4;

#define MFMA16(a, b, c) __builtin_amdgcn_mfma_f32_16x16x32_bf16(a, b, c, 0, 0, 0)

__device__ __forceinline__ float fast_rcp(float x) { return __builtin_amdgcn_rcpf(x); }
__device__ __forceinline__ float silu_f(float x) { return x * fast_rcp(1.f + __expf(-x)); }
__device__ __forceinline__ bf16x8 cvt8(float4 a, float4 b) {
  bf16x8 o;
  o[0]=(bf16)a.x; o[1]=(bf16)a.y; o[2]=(bf16)a.z; o[3]=(bf16)a.w;
  o[4]=(bf16)b.x; o[5]=(bf16)b.y; o[6]=(bf16)b.z; o[7]=(bf16)b.w;
  return o;
}

// ---------------- ws layout (round-5 proven) ----------------
constexpr long WB_IPW1 = 0;
constexpr long WB_IPW2 = 49152;
constexpr long WB_QKV  = 114688;
constexpr long WB_WO   = 704512;
constexpr long WB_W1   = 901120;
constexpr long WB_W2   = 1687552;
constexpr long WB_CPW1 = 2670592;
constexpr long F_ZIN = 5472256;
constexpr long F_G   = F_ZIN + 512L*192*4;
constexpr long F_H   = F_G + 1024;
constexpr long F_QKV = F_H + 512L*256*4;
constexpr long F_S   = F_QKV + 512L*768*4;
constexpr long F_VT  = F_S + 4L*512*512*4;
constexpr long F_O   = F_VT + 4L*64*512*2;
constexpr long F_T1  = F_O + 512L*256*4;
constexpr long O_W2P  = F_T1 + 512L*256*4;
constexpr long O_WDP  = O_W2P + 131072;
constexpr long O_B512 = O_WDP + 262144;

// ---------------- prep — round-5 verbatim ----------------
__global__ __launch_bounds__(256) void prep_kernel(
    const float* __restrict__ s_ipw1, const float* __restrict__ s_ipw2,
    const float* __restrict__ s_qkv,  const float* __restrict__ s_wo,
    const float* __restrict__ s_w1,   const float* __restrict__ s_w2,
    const float* __restrict__ s_dpw1, const float* __restrict__ s_dpw2,
    const float* __restrict__ s_cpw1, bf16* __restrict__ dst,
    const float* __restrict__ z, const int* __restrict__ at, const float* __restrict__ emb,
    const float* __restrict__ zg, const float* __restrict__ gw1, const float* __restrict__ gb1,
    const float* __restrict__ gw2, const float* __restrict__ gb2,
    const float* __restrict__ dpb1,
    float* __restrict__ zi, bf16* __restrict__ w2p, bf16* __restrict__ wdp,
    float* __restrict__ g, float* __restrict__ bias512)
{
  __shared__ float zs[128];
  __shared__ float ts[256];
  const int b = blockIdx.x, tid = threadIdx.x;
  if (b < 2672) {
    long v = (long)b * 256 + tid;
    if (v >= 684032) return;
    const float* src; long off;
    if (v < 176128) {
      if (v < 12288)      { src = s_ipw1; off = 0; }
      else if (v < 28672) { src = s_ipw2; off = 12288; }
      else                { src = s_qkv;  off = 28672; }
    } else if (v < 618496) {
      if (v < 225280)      { src = s_wo; off = 176128; }
      else if (v < 421888) { src = s_w1; off = 225280; }
      else                 { src = s_w2; off = 421888; }
    } else {
      if (v < 651264)      { src = s_dpw1; off = 618496; }
      else if (v < 667648) { src = s_dpw2; off = 651264; }
      else                 { src = s_cpw1; off = 667648; }
    }
    long e = (v - off) * 4;
    float4 f = *(const float4*)&src[e];
    bf16* d = dst + off * 4 + e;
    d[0] = (bf16)f.x; d[1] = (bf16)f.y; d[2] = (bf16)f.z; d[3] = (bf16)f.w;
  } else if (b < 3056) {
    int idx = (b - 2672) * 256 + tid;
    int n = idx / 192, c = idx - n * 192;
    zi[idx] = (c < 128) ? z[n * 128 + c] : emb[at[n] * 64 + (c - 128)];
  } else if (b < 3088) {
    int f = (b - 3056) * 256 + tid;
    int l15 = f & 15, kq = (f >> 4) & 3, ks = (f >> 6) & 7, nt = f >> 9;
    int n = nt * 16 + l15, k0 = ks * 32 + kq * 8;
    float4 v0 = *(const float4*)&s_dpw2[n * 256 + k0];
    float4 v1 = *(const float4*)&s_dpw2[n * 256 + k0 + 4];
    *(bf16x8*)&w2p[(long)f * 8] = cvt8(v0, v1);
  } else if (b < 3216) {
    int v = (b - 3088) * 256 + tid;
    int r = v >> 6, c4 = (v & 63) << 2;
    long src = (r < 256) ? ((long)r * 512 + c4) : ((long)(r - 256) * 512 + 256 + c4);
    float4 f = *(const float4*)&s_dpw1[src];
    bf16* d = &wdp[r * 256 + c4];
    d[0]=(bf16)f.x; d[1]=(bf16)f.y; d[2]=(bf16)f.z; d[3]=(bf16)f.w;
  } else if (b == 3216) {
    if (tid < 128) zs[tid] = zg[tid];
    __syncthreads();
    float s = gb1[tid];
    for (int k = 0; k < 128; ++k) s += zs[k] * gw1[tid * 128 + k];
    ts[tid] = silu_f(s);
    __syncthreads();
    float s2 = gb2[tid];
    for (int k = 0; k < 256; ++k) s2 += ts[k] * gw2[tid * 256 + k];
    g[tid] = s2;
  } else {
    bias512[tid] = dpb1[tid];
    bias512[256 + tid] = 0.f;
  }
}

// ---------------- generic MFMA GEMM — round-2/5 verbatim ----------------
template<int ACT, typename WT>
__global__ __launch_bounds__(256) void gemm_kernel(
    const float* __restrict__ A, int lda, long sA,
    const WT* __restrict__ W, int ldw, long sW,
    const float* __restrict__ bias,
    const float* __restrict__ R, int ldr, long sR,
    float* __restrict__ C, int ldc, long sC, int K)
{
  const int bz = blockIdx.z;
  A += (long)bz * sA;  W += (long)bz * sW;  C += (long)bz * sC;
  if (R) R += (long)bz * sR;
  const int m0 = blockIdx.x * 64, n0 = blockIdx.y * 64;
  __shared__ bf16 As[64][72];
  __shared__ bf16 Ws[64][72];
  const int tid = threadIdx.x;
  const int lane = tid & 63, wid = tid >> 6;
  const int wm = (wid & 1) * 32, wn = (wid >> 1) * 32;
  const int rr = lane & 15, kg = (lane >> 4) << 3;
  f32x4 acc[2][2] = {};
  for (int k0 = 0; k0 < K; k0 += 64) {
#pragma unroll
    for (int r = 0; r < 4; ++r) {
      int lin = tid + r * 256;
      int row = lin >> 4, kc = (lin & 15) << 2;
      {
        const float* p = &A[(long)(m0 + row) * lda + k0 + kc];
        float4 v = *(const float4*)p;
        As[row][kc] = (bf16)v.x; As[row][kc + 1] = (bf16)v.y;
        As[row][kc + 2] = (bf16)v.z; As[row][kc + 3] = (bf16)v.w;
      }
      {
        const WT* p = &W[(long)(n0 + row) * ldw + k0 + kc];
        if constexpr (sizeof(WT) == 4) {
          float4 v = *(const float4*)p;
          Ws[row][kc] = (bf16)v.x; Ws[row][kc + 1] = (bf16)v.y;
          Ws[row][kc + 2] = (bf16)v.z; Ws[row][kc + 3] = (bf16)v.w;
        } else {
          *(uint2*)&Ws[row][kc] = *(const uint2*)p;
        }
      }
    }
    __syncthreads();
#pragma unroll
    for (int ks = 0; ks < 2; ++ks) {
      const int kk = ks * 32 + kg;
      bf16x8 a0 = *(const bf16x8*)&As[wm + rr][kk];
      bf16x8 a1 = *(const bf16x8*)&As[wm + 16 + rr][kk];
      bf16x8 b0 = *(const bf16x8*)&Ws[wn + rr][kk];
      bf16x8 b1 = *(const bf16x8*)&Ws[wn + 16 + rr][kk];
      acc[0][0] = MFMA16(a0, b0, acc[0][0]);
      acc[0][1] = MFMA16(a0, b1, acc[0][1]);
      acc[1][0] = MFMA16(a1, b0, acc[1][0]);
      acc[1][1] = MFMA16(a1, b1, acc[1][1]);
    }
    __syncthreads();
  }
  const int rg = lane >> 4;
#pragma unroll
  for (int mi = 0; mi < 2; ++mi)
#pragma unroll
    for (int ni = 0; ni < 2; ++ni)
#pragma unroll
      for (int r = 0; r < 4; ++r) {
        int gm = m0 + wm + mi * 16 + rg * 4 + r;
        int gn = n0 + wn + ni * 16 + rr;
        float v = acc[mi][ni][r];
        if (bias) v += bias[gn];
        if (R) v += R[(long)gm * ldr + gn];
        if (ACT == 1) v = silu_f(v);
        else if (ACT == 2) v = fmaxf(v, 0.f);
        C[(long)gm * ldc + gn] = v;
      }
}

// ---------------- merged softmax (b<2048) + V-transpose (b>=2048) ----------------
__global__ __launch_bounds__(256) void softvt_kernel(
    float* __restrict__ S, const float* __restrict__ qkv, bf16* __restrict__ vt)
{
  const int b = blockIdx.x, tid = threadIdx.x;
  if (b < 2048) {
    float* row = S + (long)b * 512;
    float a = row[tid] * 0.125f, e1v = row[tid + 256] * 0.125f;
    float m = fmaxf(a, e1v);
#pragma unroll
    for (int o = 1; o < 64; o <<= 1) m = fmaxf(m, __shfl_xor(m, o));
    __shared__ float red[4];
    __shared__ float red2[4];
    int wid = tid >> 6;
    if ((tid & 63) == 0) red[wid] = m;
    __syncthreads();
    m = fmaxf(fmaxf(red[0], red[1]), fmaxf(red[2], red[3]));
    float e0 = __expf(a - m), e1 = __expf(e1v - m);
    float s = e0 + e1;
#pragma unroll
    for (int o = 1; o < 64; o <<= 1) s += __shfl_xor(s, o);
    if ((tid & 63) == 0) red2[wid] = s;
    __syncthreads();
    s = red2[0] + red2[1] + red2[2] + red2[3];
    float inv = fast_rcp(s);
    row[tid] = e0 * inv; row[tid + 256] = e1 * inv;
  } else {
    int idx = (b - 2048) * 256 + tid;
    int hh = idx >> 15;
    int r = idx & 32767;
    int d = r >> 9, n = r & 511;
    vt[idx] = (bf16)qkv[(long)n * 768 + 512 + hh * 64 + d];
  }
}

// ---------------- LayerNorm — round-5 verbatim ----------------
__global__ __launch_bounds__(256) void ln_kernel(
    const float* __restrict__ X, const float* __restrict__ sc,
    const float* __restrict__ bi, float* __restrict__ Y)
{
  int row = blockIdx.x, tid = threadIdx.x;
  float v = X[(long)row * 256 + tid];
  float s = v;
#pragma unroll
  for (int o = 1; o < 64; o <<= 1) s += __shfl_xor(s, o);
  __shared__ float r1[4];
  __shared__ float r2[4];
  if ((tid & 63) == 0) r1[tid >> 6] = s;
  __syncthreads();
  float mean = (r1[0] + r1[1] + r1[2] + r1[3]) * (1.f / 256.f);
  float d = v - mean;
  float t = d * d;
#pragma unroll
  for (int o = 1; o < 64; o <<= 1) t += __shfl_xor(t, o);
  if ((tid & 63) == 0) r2[tid >> 6] = t;
  __syncthreads();
  float var = (r2[0] + r2[1] + r2[2] + r2[3]) * (1.f / 256.f);
  Y[(long)row * 256 + tid] = d * rsqrtf(var + 1e-5f) * sc[tid] + bi[tid];
}

// ---------------- pair2 v4: 32-pair chunks, LDS double-buffer, 1 barrier/chunk ----------------
// build(c+1) sits in the same barrier-free region as MFMA(c) + epilogue(c):
// independent LDS arrays -> compiler interleaves trans ops into MFMA gaps.
#define P2_BUILD(CIDX, TBUF)                                                     \
  {                                                                              \
    const int j0b = jbase + (CIDX) * 32;                                         \
    const float* ajp = aj + (long)(j0b + pp) * 512;                              \
    _Pragma("unroll")                                                            \
    for (int r = 0; r < 4; ++r) {                                                \
      int kk = kb + 8 * r;                                                       \
      float4 a0 = *(const float4*)(ajp + kk * 8);                                \
      float4 a1 = *(const float4*)(ajp + kk * 8 + 4);                            \
      const float* aip = ai_s + kk * 8;                                          \
      bf16x8 tv;                                                                 \
      tv[0] = (bf16)silu_f(a0.x + aip[0]); tv[1] = (bf16)silu_f(a0.y + aip[1]);  \
      tv[2] = (bf16)silu_f(a0.z + aip[2]); tv[3] = (bf16)silu_f(a0.w + aip[3]);  \
      tv[4] = (bf16)silu_f(a1.x + aip[4]); tv[5] = (bf16)silu_f(a1.y + aip[5]);  \
      tv[6] = (bf16)silu_f(a1.z + aip[6]); tv[7] = (bf16)silu_f(a1.w + aip[7]);  \
      *(bf16x8*)&TBUF[(kk * 32 + pp) * 8] = tv;                                  \
    }                                                                            \
  }

#define P2_MFMA(TBUF, ACC)                                                       \
  _Pragma("unroll")                                                              \
  for (int ks = 0; ks < 8; ++ks) {                                               \
    bf16x8 af0 = *(const bf16x8*)&TBUF[((ks * 4 + kq) * 32 + l15) * 8];          \
    bf16x8 af1 = *(const bf16x8*)&TBUF[((ks * 4 + kq) * 32 + 16 + l15) * 8];     \
    _Pragma("unroll")                                                            \
    for (int nt = 0; nt < 4; ++nt) {                                             \
      bf16x8 bfv = *(const bf16x8*)(w2base + (long)(nt * 8 + ks) * 512);         \
      ACC[0][nt] = MFMA16(af0, bfv, ACC[0][nt]);                                 \
      ACC[1][nt] = MFMA16(af1, bfv, ACC[1][nt]);                                 \
    }                                                                            \
  }

#define P2_EPI(ACC, PBUF)                                                        \
  _Pragma("unroll")                                                              \
  for (int Mt = 0; Mt < 2; ++Mt)                                                 \
    _Pragma("unroll")                                                            \
    for (int r = 0; r < 4; ++r) {                                                \
      float s = silu_f(ACC[Mt][0][r] + b2v[0]) * w3v[0]                          \
              + silu_f(ACC[Mt][1][r] + b2v[1]) * w3v[1]                          \
              + silu_f(ACC[Mt][2][r] + b2v[2]) * w3v[2]                          \
              + silu_f(ACC[Mt][3][r] + b2v[3]) * w3v[3];                         \
      s += __shfl_xor(s, 1); s += __shfl_xor(s, 2);                              \
      s += __shfl_xor(s, 4); s += __shfl_xor(s, 8);                              \
      if (l15 == 0) PBUF[Mt * 16 + kq * 4 + r][w] = s;                           \
    }

#define P2_DIST(CIDX, PBUF)                                                      \
  if (tid < 32) {                                                                \
    float s = PBUF[tid][0] + PBUF[tid][1] + PBUF[tid][2] + PBUF[tid][3] + b3v;   \
    float dd = fmaxf(s, 0.f) + log1pf(__expf(-fabsf(s)));                        \
    dout[(long)i * 512 + jbase + (CIDX) * 32 + tid] = dd;                        \
  }

__global__ __launch_bounds__(256, 2) void pair2_kernel(
    const float* __restrict__ ai, const float* __restrict__ aj,
    const bf16* __restrict__ W2P, const float* __restrict__ b2g,
    const float* __restrict__ w3g, const float* __restrict__ b3p,
    float* __restrict__ dout)
{
  __shared__ float ai_s[256];
  __shared__ bf16 t0_s[32 * 256];
  __shared__ bf16 t1_s[32 * 256];
  __shared__ float p0_s[32][4];
  __shared__ float p1_s[32][4];
  const int tid = threadIdx.x, lane = tid & 63, w = tid >> 6;
  const int l15 = lane & 15, kq = lane >> 4;
  const int pp = tid & 31, kb = tid >> 5;
  const int i = blockIdx.x >> 1, half = blockIdx.x & 1;
  const int jbase = half * 256;
  const float b3v = b3p[0];

  ai_s[tid] = ai[(long)i * 512 + tid];

  float b2v[4], w3v[4];
#pragma unroll
  for (int nt = 0; nt < 4; ++nt) {
    int ntg = w * 4 + nt;
    b2v[nt] = b2g[ntg * 16 + l15];
    w3v[nt] = w3g[ntg * 16 + l15];
  }
  const bf16* w2base = W2P + ((long)((w * 128 + kq) * 16 + l15)) * 8;
  __syncthreads();

  P2_BUILD(0, t0_s);
  __syncthreads();
#pragma unroll 1
  for (int cp = 0; cp < 4; ++cp) {
    const int c0 = cp * 2, c1 = cp * 2 + 1;
    {
      f32x4 acc[2][4] = {};
      P2_MFMA(t0_s, acc);
      P2_BUILD(c1, t1_s);
      P2_EPI(acc, p0_s);
    }
    __syncthreads();
    P2_DIST(c0, p0_s);
    {
      f32x4 acc[2][4] = {};
      P2_MFMA(t1_s, acc);
      if (cp < 3) P2_BUILD(c1 + 1, t0_s);
      P2_EPI(acc, p1_s);
    }
    __syncthreads();
    P2_DIST(c1, p1_s);
  }
}

// ---------------- symmetrize ----------------
__global__ __launch_bounds__(256) void sym_kernel(float* __restrict__ dist)
{
  int idx = blockIdx.x * 256 + threadIdx.x;
  int i = idx >> 9, j = idx & 511;
  if (i < j) {
    float a = dist[idx];
    float b = dist[(long)j * 512 + i];
    float m = 0.5f * (a + b);
    dist[idx] = m;
    dist[(long)j * 512 + i] = m;
  }
}

// ---------------- coordinate head ----------------
__global__ __launch_bounds__(256) void coord_kernel(
    const float* __restrict__ ct, const float* __restrict__ w2,
    const float* __restrict__ b2, float* __restrict__ out)
{
  int t = blockIdx.x * 256 + threadIdx.x;
  if (t >= 1536) return;
  int row = t / 3, c = t - row * 3;
  float s = b2[c];
  const float* a = &ct[(long)row * 256];
  const float* wp = &w2[c * 256];
  for (int k = 0; k < 256; ++k) s += a[k] * wp[k];
  out[t] = s;
}

extern "C" void kernel_launch(void* const* d_in, const int* in_sizes, int n_in,
                              void* d_out, int out_size, void* d_ws, size_t ws_size,
                              hipStream_t stream) {
  const float* z        = (const float*)d_in[0];
  const float* z_global = (const float*)d_in[1];
  const int*   atom_t   = (const int*)d_in[2];
  const float* emb      = (const float*)d_in[3];
  const float* ip_w1 = (const float*)d_in[4];  const float* ip_b1 = (const float*)d_in[5];
  const float* ip_w2 = (const float*)d_in[6];  const float* ip_b2 = (const float*)d_in[7];
  const float* gp_w1 = (const float*)d_in[8];  const float* gp_b1 = (const float*)d_in[9];
  const float* gp_w2 = (const float*)d_in[10]; const float* gp_b2 = (const float*)d_in[11];
  const float* wqkv  = (const float*)d_in[12]; const float* bqkv  = (const float*)d_in[13];
  const float* wo    = (const float*)d_in[14]; const float* bo    = (const float*)d_in[15];
  const float* ln1s  = (const float*)d_in[16]; const float* ln1b  = (const float*)d_in[17];
  const float* w1    = (const float*)d_in[18]; const float* b1    = (const float*)d_in[19];
  const float* w2    = (const float*)d_in[20]; const float* b2    = (const float*)d_in[21];
  const float* ln2s  = (const float*)d_in[22]; const float* ln2b  = (const float*)d_in[23];
  const float* dpw1  = (const float*)d_in[24]; const float* dpb1  = (const float*)d_in[25];
  const float* dpw2  = (const float*)d_in[26]; const float* dpb2  = (const float*)d_in[27];
  const float* dpw3  = (const float*)d_in[28]; const float* dpb3  = (const float*)d_in[29];
  const float* cpw1  = (const float*)d_in[30]; const float* cpb1  = (const float*)d_in[31];
  const float* cpw2  = (const float*)d_in[32]; const float* cpb2  = (const float*)d_in[33];

  char* ws = (char*)d_ws;
  bf16*  WB   = (bf16*)ws;
  float* zin  = (float*)(ws + F_ZIN);
  float* g    = (float*)(ws + F_G);
  float* h    = (float*)(ws + F_H);
  float* qkv  = (float*)(ws + F_QKV);
  float* S    = (float*)(ws + F_S);
  bf16*  Vt   = (bf16*)(ws + F_VT);
  float* o    = (float*)(ws + F_O);
  float* t1   = (float*)(ws + F_T1);
  bf16*  W2P  = (bf16*)(ws + O_W2P);
  bf16*  WDP  = (bf16*)(ws + O_WDP);
  float* b512 = (float*)(ws + O_B512);
  float* ff1  = S;
  float* aiaj = S;
  float* out  = (float*)d_out;
  float* xout = out;
  float* dist = out + 1536;

  prep_kernel<<<3218, 256, 0, stream>>>(ip_w1, ip_w2, wqkv, wo, w1, w2, dpw1, dpw2, cpw1, WB,
      z, atom_t, emb, z_global, gp_w1, gp_b1, gp_w2, gp_b2, dpb1,
      zin, W2P, WDP, g, b512);

  gemm_kernel<1, bf16><<<dim3(8, 4, 1), 256, 0, stream>>>(zin, 192, 0, WB + WB_IPW1, 192, 0,
      ip_b1, nullptr, 0, 0, t1, 256, 0, 192);
  gemm_kernel<0, bf16><<<dim3(8, 4, 1), 256, 0, stream>>>(t1, 256, 0, WB + WB_IPW2, 256, 0,
      ip_b2, g, 0, 0, h, 256, 0, 256);

  for (int l = 0; l < 3; ++l) {
    const bf16* wq = WB + WB_QKV + (long)l * 768 * 256;
    gemm_kernel<0, bf16><<<dim3(8, 12, 1), 256, 0, stream>>>(h, 256, 0, wq, 256, 0,
        bqkv + l * 768, nullptr, 0, 0, qkv, 768, 0, 256);
    gemm_kernel<0, float><<<dim3(8, 8, 4), 256, 0, stream>>>(qkv, 768, 64, qkv + 256, 768, 64,
        nullptr, nullptr, 0, 0, S, 512, 262144, 64);
    softvt_kernel<<<2560, 256, 0, stream>>>(S, qkv, Vt);
    gemm_kernel<0, bf16><<<dim3(8, 1, 4), 256, 0, stream>>>(S, 512, 262144, Vt, 512, 32768,
        nullptr, nullptr, 0, 0, o, 256, 64, 512);
    gemm_kernel<0, bf16><<<dim3(8, 4, 1), 256, 0, stream>>>(o, 256, 0,
        WB + WB_WO + (long)l * 65536, 256, 0, bo + l * 256, h, 256, 0, t1, 256, 0, 256);
    ln_kernel<<<512, 256, 0, stream>>>(t1, ln1s + l * 256, ln1b + l * 256, h);
    gemm_kernel<2, bf16><<<dim3(8, 16, 1), 256, 0, stream>>>(h, 256, 0,
        WB + WB_W1 + (long)l * 262144, 256, 0, b1 + l * 1024, nullptr, 0, 0, ff1, 1024, 0, 256);
    gemm_kernel<0, bf16><<<dim3(8, 4, 1), 256, 0, stream>>>(ff1, 1024, 0,
        WB + WB_W2 + (long)l * 262144, 1024, 0, b2 + l * 256, h, 256, 0, t1, 256, 0, 1024);
    ln_kernel<<<512, 256, 0, stream>>>(t1, ln2s + l * 256, ln2b + l * 256, h);
  }

  gemm_kernel<0, bf16><<<dim3(8, 8, 1), 256, 0, stream>>>(h, 256, 0, WDP, 256, 0,
      b512, nullptr, 0, 0, aiaj, 512, 0, 256);
  pair2_kernel<<<1024, 256, 0, stream>>>(aiaj, aiaj + 256, W2P, dpb2, dpw3, dpb3, dist);
  sym_kernel<<<1024, 256, 0, stream>>>(dist);
  gemm_kernel<1, bf16><<<dim3(8, 4, 1), 256, 0, stream>>>(h, 256, 0, WB + WB_CPW1, 256, 0,
      cpb1, nullptr, 0, 0, t1, 256, 0, 256);
  coord_kernel<<<6, 256, 0, stream>>>(t1, cpw2, cpb2, xout);
}